// Round 7
// baseline (1474.671 us; speedup 1.0000x reference)
//
#include <hip/hip_runtime.h>
#include <math.h>

// FNO1d: B=64, N=8192, F_IN=2, W=64, L=5, M=16, PAD=9 -> NLEN=8201
#define NLEN 8201
#define NB 64
#define W 64
#define M 16
#define NL 5
#define TWO_PI 6.283185307179586476925286766559
#define NT_STAT 514    // static B-frag n-tiles (n < 8224); OOB tiles clamp there
#define NSTEPS 257     // DFT twiddle A-frag K-steps of 32 (covers n < 8224)
#define NBLK 33        // 33 x 256 = 8448 logical cols (8201 valid, rest junk-safe)

typedef unsigned short u16;
typedef __attribute__((ext_vector_type(8))) short bf16x8;   // MFMA A/B frag (4 VGPR)
typedef __attribute__((ext_vector_type(4))) float f32x4;    // MFMA C/D frag
typedef __attribute__((ext_vector_type(4))) short short4v;
typedef __attribute__((ext_vector_type(8))) short short8v;

// ---- bf16 split-precision helpers (x = hi + lo, both RN bf16) ----
__device__ __forceinline__ u16 bf16rn(float x) {
    unsigned u = __float_as_uint(x);
    unsigned r = (u + 0x7fffu + ((u >> 16) & 1u)) >> 16;
    return (u16)r;
}
__device__ __forceinline__ float bf16tof(u16 h) {
    return __uint_as_float(((unsigned)h) << 16);
}
__device__ __forceinline__ void bf16split(float x, u16& h, u16& lo) {
    h = bf16rn(x);
    lo = bf16rn(x - bf16tof(h));
}

__device__ __forceinline__ short8v cat4(short4v a, short4v b) {
    short8v r;
    r[0] = a[0]; r[1] = a[1]; r[2] = a[2]; r[3] = a[3];
    r[4] = b[0]; r[5] = b[1]; r[6] = b[2]; r[7] = b[3];
    return r;
}

__device__ __forceinline__ void atomicAddF(float* p, float v) {
    __hip_atomic_fetch_add(p, v, __ATOMIC_RELAXED, __HIP_MEMORY_SCOPE_AGENT);
}

// Both MFMA operand sides always use the SAME (lane>>4, e) -> kk bijection, so
// the hardware's exact within-K ordering cancels out of every contraction.
//   main GEMM:     kk(g,e) = g*4 + (e&3) + 16*(e>>2)
//   DFT epilogue:  nloc(g,e) = g*8 + e
//
// v lives in GLOBAL memory pre-fragmented ("Vf"): per (b, blk) a 64 KB tile
// Vf[plane(4)=ks*2+hl][nt(16)][lane(64)][e(8)] of u16. Wave wv's GEMM B-frags
// are the nt = wv*2+ntl slices -> DISJOINT per wave -> loaded straight from
// global to registers (coalesced 16B/lane). The format is an IDENTITY between
// producer epilogue registers and consumer B-frags (enables the last-layer
// conv+projection fusion fully in registers).

// Branchless gelu: A&S 7.1.26 erf (|err| <= 1.5e-7), rcp+exp fast paths.
__device__ __forceinline__ float gelu_f(float x) {
    float s = x * 0.70710678118654752f;
    float a = fabsf(s);
    float t = __builtin_amdgcn_rcpf(fmaf(0.3275911f, a, 1.0f));
    float p = fmaf(1.061405429f, t, -1.453152027f);
    p = fmaf(p, t, 1.421413741f);
    p = fmaf(p, t, -0.284496736f);
    p = fmaf(p, t, 0.254829592f);
    p = p * t;
    float e = __expf(-a * a);
    float er = copysignf(fmaf(-p, e, 1.0f), s);
    float h = 0.5f * x;
    return fmaf(h, er, h);
}

// Static B-frags for main-GEMM ks=2 (U rows 64..95 = [cos1..15|sin1..15|1|0]).
__global__ __launch_bounds__(256) void kstat(u16* __restrict__ Ustat) {
    int nt = blockIdx.x;             // 0..NT_STAT-1
    int t = threadIdx.x;
    for (int s = t; s < 512; s += 256) {
        int lane = s >> 3, e = s & 7;
        int kk = ((lane >> 4) << 2) + (e & 3) + ((e >> 2) << 4);
        int r = 64 + kk;
        int n = nt * 16 + (lane & 15);
        float val;
        if (r < 94) {
            int k = (r < 79) ? (r - 63) : (r - 78);
            long long mm = ((long long)k * (long long)n) % NLEN;
            double th = (TWO_PI / (double)NLEN) * (double)mm;
            double sv, cv;
            sincos(th, &sv, &cv);
            val = (float)((r < 79) ? cv : sv);
        } else {
            val = (r == 94) ? 1.0f : 0.0f;
        }
        u16 h, lo;
        bf16split(val, h, lo);
        size_t base = ((size_t)nt * 64 + lane) * 8 + e;
        Ustat[base] = h;
        Ustat[(size_t)NT_STAT * 512 + base] = lo;
    }
}

// Twiddle A-frags for the fused DFT: Tdft[nstep][kcT(2)][hl(2)][lane][e].
// A[m=kc][n]: kc<16 -> cos(2pi*kc*n/NLEN); kc>=16 -> -sin(2pi*(kc-16)*n/NLEN).
__global__ __launch_bounds__(256) void kdtab(u16* __restrict__ Tdft) {
    int nstep = blockIdx.x;
    int t = threadIdx.x;
    for (int s = t; s < 1024; s += 256) {     // kcT(2) x lane(64) x e(8)
        int e = s & 7, lane = (s >> 3) & 63, kcT = s >> 9;
        int kc = kcT * 16 + (lane & 15);
        int n = nstep * 32 + ((lane >> 4) << 3) + e;
        int k = kc & 15;
        long long m = ((long long)k * (long long)n) % NLEN;
        double th = (TWO_PI / (double)NLEN) * (double)m;
        double sv, cv;
        sincos(th, &sv, &cv);
        float val = (kc < 16) ? (float)cv : (float)(-sv);
        u16 h, lo;
        bf16split(val, h, lo);
        size_t base = (((size_t)nstep * 2 + kcT) * 2) * 512 + lane * 8 + e;
        Tdft[base] = h;
        Tdft[base + 512] = lo;
    }
}

// Pack cw (all 5 layers) into A-frags: AcwBuf[l][ks(2)][hl(2)][mt(4)][lane][e].
__global__ __launch_bounds__(256) void kprep(const float* __restrict__ cw,
                                             u16* __restrict__ AcwBuf) {
    int l = blockIdx.x;
    int t = threadIdx.x;
    const float* cwl = cw + (size_t)l * W * W;
    u16* ob = AcwBuf + (size_t)l * 8192;
    for (int s = t; s < 4096; s += 256) {
        int e = s & 7, lane = (s >> 3) & 63, mt = (s >> 9) & 3, ks = s >> 11;
        int kk = ((lane >> 4) << 2) + (e & 3) + ((e >> 2) << 4);
        int k = ks * 32 + kk;
        int o = mt * 16 + (lane & 15);
        u16 h, lo;
        bf16split(cwl[o * 64 + k], h, lo);
        ob[(((size_t)ks * 2 + 0) * 4 + mt) * 512 + lane * 8 + e] = h;
        ob[(((size_t)ks * 2 + 1) * 4 + mt) * 512 + lane * 8 + e] = lo;
    }
}

// Pack w1 (64k x 128h) into A-frags: Aw1[ks(2)][hl(2)][mt(8)][lane][e].
__global__ __launch_bounds__(256) void kprep2(const float* __restrict__ w1,
                                              u16* __restrict__ Aw1) {
    int t = threadIdx.x;
    for (int s = t; s < 8192; s += 256) {    // ks(2) x mt(8) x lane(64) x e(8)
        int e = s & 7, lane = (s >> 3) & 63, mt = (s >> 9) & 7, ks = s >> 12;
        int kk = ((lane >> 4) << 2) + (e & 3) + ((e >> 2) << 4);
        int k = ks * 32 + kk;
        int h = mt * 16 + (lane & 15);
        u16 hh, lo;
        bf16split(w1[k * 128 + h], hh, lo);
        Aw1[(((size_t)ks * 2 + 0) * 8 + mt) * 512 + lane * 8 + e] = hh;
        Aw1[(((size_t)ks * 2 + 1) * 8 + mt) * 512 + lane * 8 + e] = lo;
    }
}

// Fused DFT of a 64o x 32n output tile held in registers (hv/lv), using a
// 4 KB/wave LDS pack region (two o-halves, wave-private, in-order DS pipe
// makes the overwrite safe) and an 8 KB shared f32 accumulator via LDS
// atomics. racc must be zeroed + barriered BEFORE this is called.
__device__ __forceinline__ void dft_fused(u16* packW_w, float* racc,
        const short4v (&hv)[4][2], const short4v (&lv)[4][2],
        int wv, int lane, int t, int blk, int n0,
        const u16* __restrict__ Tdft, float* __restrict__ FpB, int atomicMode) {
    int r4 = (lane >> 4) << 2;
    int g = lane >> 4;
    int nstep = blk * 8 + wv;
    if (nstep > NSTEPS - 1) nstep = NSTEPS - 1;   // OOB waves have zeroed B
    const u16* at = Tdft + (size_t)nstep * 2048;
    bf16x8 Th0 = *(const bf16x8*)(at + lane * 8);
    bf16x8 Tl0 = *(const bf16x8*)(at + 512 + lane * 8);
    bf16x8 Th1 = *(const bf16x8*)(at + 1024 + lane * 8);
    bf16x8 Tl1 = *(const bf16x8*)(at + 1536 + lane * 8);
    f32x4 dacc[2][4];
    #pragma unroll
    for (int kt = 0; kt < 2; kt++)
        #pragma unroll
        for (int ot = 0; ot < 4; ot++) dacc[kt][ot] = (f32x4){0.f, 0.f, 0.f, 0.f};

    #pragma unroll
    for (int half = 0; half < 2; half++) {
        // pack o-range [half*32, half*32+32) x 32n, swizzled
        #pragma unroll
        for (int ntl = 0; ntl < 2; ntl++) {
            int nl = ntl * 16 + (lane & 15);
            bool ok = (n0 + wv * 32 + nl) <= 8200;   // DFT covers n in [0,8200]
            #pragma unroll
            for (int mtl = 0; mtl < 2; mtl++) {
                int mt = half * 2 + mtl;
                #pragma unroll
                for (int j = 0; j < 4; j++) {
                    int op = mtl * 16 + r4 + j;       // o' within half: 0..31
                    u16 h  = ok ? (u16)hv[mt][ntl][j] : (u16)0;
                    u16 lo = ok ? (u16)lv[mt][ntl][j] : (u16)0;
                    int raw = op * 128 + nl * 2;
                    int swz = (op & 7) << 4;
                    packW_w[(raw ^ swz) >> 1] = h;
                    packW_w[((raw + 64) ^ swz) >> 1] = lo;
                }
            }
        }
        // contract vs Tdft (reads complete before next half's overwrite:
        // per-wave DS ops are in-order; compiler inserts lgkmcnt)
        #pragma unroll
        for (int otl = 0; otl < 2; otl++) {
            int op = otl * 16 + (lane & 15);
            int swz = (op & 7) << 4;
            bf16x8 Bh = *(const bf16x8*)(packW_w + (((op * 128 + g * 16) ^ swz) >> 1));
            bf16x8 Bl = *(const bf16x8*)(packW_w + (((op * 128 + 64 + g * 16) ^ swz) >> 1));
            int ot = half * 2 + otl;
            dacc[0][ot] = __builtin_amdgcn_mfma_f32_16x16x32_bf16(Th0, Bh, dacc[0][ot], 0, 0, 0);
            dacc[0][ot] = __builtin_amdgcn_mfma_f32_16x16x32_bf16(Th0, Bl, dacc[0][ot], 0, 0, 0);
            dacc[0][ot] = __builtin_amdgcn_mfma_f32_16x16x32_bf16(Tl0, Bh, dacc[0][ot], 0, 0, 0);
            dacc[0][ot] = __builtin_amdgcn_mfma_f32_16x16x32_bf16(Tl0, Bl, dacc[0][ot], 0, 0, 0);
            dacc[1][ot] = __builtin_amdgcn_mfma_f32_16x16x32_bf16(Th1, Bh, dacc[1][ot], 0, 0, 0);
            dacc[1][ot] = __builtin_amdgcn_mfma_f32_16x16x32_bf16(Th1, Bl, dacc[1][ot], 0, 0, 0);
            dacc[1][ot] = __builtin_amdgcn_mfma_f32_16x16x32_bf16(Tl1, Bh, dacc[1][ot], 0, 0, 0);
            dacc[1][ot] = __builtin_amdgcn_mfma_f32_16x16x32_bf16(Tl1, Bl, dacc[1][ot], 0, 0, 0);
        }
    }

    // cross-wave reduce via LDS atomics into racc[kc32][o64]
    #pragma unroll
    for (int kt = 0; kt < 2; kt++)
        #pragma unroll
        for (int ot = 0; ot < 4; ot++) {
            int oo = ot * 16 + (lane & 15);
            int kcb = kt * 16 + g * 4;
            atomicAdd(&racc[(kcb + 0) * 64 + oo], dacc[kt][ot][0]);
            atomicAdd(&racc[(kcb + 1) * 64 + oo], dacc[kt][ot][1]);
            atomicAdd(&racc[(kcb + 2) * 64 + oo], dacc[kt][ot][2]);
            atomicAdd(&racc[(kcb + 3) * 64 + oo], dacc[kt][ot][3]);
        }
    __syncthreads();
    {
        int idx = t * 4;
        float4 s = *(const float4*)(racc + idx);
        if (atomicMode) {
            atomicAddF(FpB + idx + 0, s.x);
            atomicAddF(FpB + idx + 1, s.y);
            atomicAddF(FpB + idx + 2, s.z);
            atomicAddF(FpB + idx + 3, s.w);
        } else {
            *(float4*)(FpB + (size_t)blk * 2048 + idx) = s;
        }
    }
}

// Fused lift + forward-DFT: lift tile in acc register layout, Vf fragment
// stores (16B/lane), then dft_fused. No f32 v exists anywhere.
__global__ __launch_bounds__(512, 6) void klift2(const float* __restrict__ x,
        const float* __restrict__ lw, const float* __restrict__ lb,
        u16* __restrict__ Vf, const u16* __restrict__ Tdft,
        float* __restrict__ Fpart, int fstride, int atomicMode) {
    __shared__ __align__(16) u16 packW[8 * 2048];   // 32 KB
    __shared__ __align__(16) float racc[2048];      // 8 KB
    int t = threadIdx.x;
    int b = blockIdx.y;
    int blk = blockIdx.x;
    int lane = t & 63;
    int wv = __builtin_amdgcn_readfirstlane(t >> 6);
    int r4 = (lane >> 4) << 2;
    u16* vfb = Vf + ((size_t)b * NBLK + blk) * 32768;
    int n0 = blk * 256;

    *(float4*)(racc + t * 4) = (float4){0.f, 0.f, 0.f, 0.f};
    __syncthreads();

    short4v hv[4][2], lv[4][2];
    #pragma unroll
    for (int ntl = 0; ntl < 2; ntl++) {
        int nt = wv * 2 + ntl;
        int n = n0 + nt * 16 + (lane & 15);
        float x0 = 0.f, x1 = 0.f;
        bool in = (n < 8192);
        if (in) {
            const float* xp = x + ((size_t)b * 8192 + n) * 2;
            x0 = xp[0]; x1 = xp[1];
        }
        #pragma unroll
        for (int mt = 0; mt < 4; mt++) {
            #pragma unroll
            for (int j = 0; j < 4; j++) {
                int o = mt * 16 + r4 + j;
                float val = in ? fmaf(x0, lw[o], fmaf(x1, lw[64 + o], lb[o])) : 0.f;
                u16 h, lo;
                bf16split(val, h, lo);
                hv[mt][ntl][j] = (short)h;
                lv[mt][ntl][j] = (short)lo;
            }
        }
        *(short8v*)(vfb + ((size_t)0 * 16 + nt) * 512 + lane * 8) = cat4(hv[0][ntl], hv[1][ntl]);
        *(short8v*)(vfb + ((size_t)1 * 16 + nt) * 512 + lane * 8) = cat4(lv[0][ntl], lv[1][ntl]);
        *(short8v*)(vfb + ((size_t)2 * 16 + nt) * 512 + lane * 8) = cat4(hv[2][ntl], hv[3][ntl]);
        *(short8v*)(vfb + ((size_t)3 * 16 + nt) * 512 + lane * 8) = cat4(lv[2][ntl], lv[3][ntl]);
    }

    dft_fused(packW + wv * 2048, racc, hv, lv, wv, lane, t, blk, n0,
              Tdft, Fpart + (size_t)b * fstride, atomicMode);
}

// Write one W-matrix value (row 64+kk, col o) into per-b ks2 A-frags (hi+lo).
__device__ __forceinline__ void wfrag(u16* wb2, int mt, int kk, int ol, float val) {
    int lane = ol + (((kk & 15) >> 2) << 4);
    int e = (kk & 3) + ((kk >> 4) << 2);
    u16 h, lo;
    bf16split(val, h, lo);
    wb2[(size_t)mt * 512 + lane * 8 + e] = h;
    wb2[(size_t)(4 + mt) * 512 + lane * 8 + e] = lo;
}

// Mode mix. Phase 1: reduce Fpart[b][0..nblk) into LDS Fs[8][64]. Phase 2:
// P = F*kern, emit spectral A-frags WfA2[b].
__global__ __launch_bounds__(256) void kmix(const float* __restrict__ Fpart,
        const float* __restrict__ kr, const float* __restrict__ ki,
        const float* __restrict__ cb, u16* __restrict__ WfA2, int l,
        int nblk, int fstride) {
    int b = blockIdx.x, kg = blockIdx.y;
    int t = threadIdx.x;
    int o = t & 63, ii = t >> 6;
    __shared__ float Fs[8][64];
    {
        const float* fp = Fpart + (size_t)b * fstride;
        int r0 = t >> 6, oo = t & 63;
        int kc0 = kg * 4 + r0;          // cos rows (Re)
        int kc1 = 16 + kg * 4 + r0;     // sin rows (Im)
        float s0 = 0.f, s1 = 0.f, s2 = 0.f, s3 = 0.f;
        int blk = 0;
        for (; blk + 2 <= nblk; blk += 2) {
            s0 += fp[(size_t)blk * 2048 + kc0 * 64 + oo];
            s1 += fp[(size_t)(blk + 1) * 2048 + kc0 * 64 + oo];
            s2 += fp[(size_t)blk * 2048 + kc1 * 64 + oo];
            s3 += fp[(size_t)(blk + 1) * 2048 + kc1 * 64 + oo];
        }
        if (blk < nblk) {
            s0 += fp[(size_t)blk * 2048 + kc0 * 64 + oo];
            s2 += fp[(size_t)blk * 2048 + kc1 * 64 + oo];
        }
        Fs[r0][oo] = s0 + s1;
        Fs[4 + r0][oo] = s2 + s3;
    }
    __syncthreads();

    const float* krl = kr + (size_t)l * W * W * M;
    const float* kil = ki + (size_t)l * W * W * M;
    float pr[4] = {0.f, 0.f, 0.f, 0.f}, pi[4] = {0.f, 0.f, 0.f, 0.f};
    for (int i = ii * 16; i < ii * 16 + 16; i++) {
        float4 kr4 = *(const float4*)(krl + ((size_t)i * W + o) * M + kg * 4);
        float4 ki4 = *(const float4*)(kil + ((size_t)i * W + o) * M + kg * 4);
        float re0 = Fs[0][i], im0 = Fs[4][i];
        float re1 = Fs[1][i], im1 = Fs[5][i];
        float re2 = Fs[2][i], im2 = Fs[6][i];
        float re3 = Fs[3][i], im3 = Fs[7][i];
        pr[0] += re0 * kr4.x - im0 * ki4.x;  pi[0] += re0 * ki4.x + im0 * kr4.x;
        pr[1] += re1 * kr4.y - im1 * ki4.y;  pi[1] += re1 * ki4.y + im1 * kr4.y;
        pr[2] += re2 * kr4.z - im2 * ki4.z;  pi[2] += re2 * ki4.z + im2 * kr4.z;
        pr[3] += re3 * kr4.w - im3 * ki4.w;  pi[3] += re3 * ki4.w + im3 * kr4.w;
    }
    __shared__ float red[4][64][8];
    #pragma unroll
    for (int c = 0; c < 4; c++) {
        red[ii][o][2 * c]     = pr[c];
        red[ii][o][2 * c + 1] = pi[c];
    }
    __syncthreads();
    if (ii == 0) {
        u16* wb2 = WfA2 + (size_t)b * 4096;
        int mt = o >> 4, ol = o & 15;
        #pragma unroll
        for (int c = 0; c < 4; c++) {
            int k = kg * 4 + c;
            float sr = red[0][o][2 * c] + red[1][o][2 * c] + red[2][o][2 * c] + red[3][o][2 * c];
            float si = red[0][o][2 * c + 1] + red[1][o][2 * c + 1] + red[2][o][2 * c + 1] + red[3][o][2 * c + 1];
            if (k == 0) {
                wfrag(wb2, mt, 30, ol, cb[l * W + o] + sr * (1.0f / (float)NLEN));
                wfrag(wb2, mt, 31, ol, 0.0f);
            } else {
                wfrag(wb2, mt, k - 1,  ol, sr * (2.0f / (float)NLEN));
                wfrag(wb2, mt, 14 + k, ol, -si * (2.0f / (float)NLEN));
            }
        }
    }
}

// Fused conv + inverse transform + gelu via bf16-split MFMA on fragment-format
// Vf, IN-PLACE, plus fused forward-DFT of the output (layers 0..3).
__global__ __launch_bounds__(512, 6) void kconv(u16* __restrict__ Vf,
        const u16* __restrict__ AcwL, const u16* __restrict__ WfA2,
        const u16* __restrict__ Ustat, const u16* __restrict__ Tdft,
        float* __restrict__ Fpart, int fstride, int atomicMode) {
    __shared__ __align__(16) u16 packW[8 * 2048];   // 32 KB
    __shared__ __align__(16) float racc[2048];      // 8 KB
    int t = threadIdx.x;
    int b = blockIdx.y;
    int blk = blockIdx.x;
    int n0 = blk * 256;
    int lane = t & 63;
    int wv = __builtin_amdgcn_readfirstlane(t >> 6);       // 0..7
    u16* vfb = Vf + ((size_t)b * NBLK + blk) * 32768;
    int nt0 = wv * 2;

    *(float4*)(racc + t * 4) = (float4){0.f, 0.f, 0.f, 0.f};
    __syncthreads();

    f32x4 acc[4][2];
    #pragma unroll
    for (int mt = 0; mt < 4; mt++)
        #pragma unroll
        for (int j = 0; j < 2; j++)
            acc[mt][j] = (f32x4){0.f, 0.f, 0.f, 0.f};

    const u16* wb2 = WfA2 + (size_t)b * 4096;
    #pragma unroll
    for (int ks = 0; ks < 3; ks++) {
        // B-frag loads inside the loop (16 regs live instead of 48)
        bf16x8 Bh[2], Bl[2];
        if (ks < 2) {
            #pragma unroll
            for (int ntl = 0; ntl < 2; ntl++) {
                Bh[ntl] = *(const bf16x8*)(vfb + (((size_t)ks * 2 + 0) * 16 + nt0 + ntl) * 512 + lane * 8);
                Bl[ntl] = *(const bf16x8*)(vfb + (((size_t)ks * 2 + 1) * 16 + nt0 + ntl) * 512 + lane * 8);
            }
        } else {
            #pragma unroll
            for (int ntl = 0; ntl < 2; ntl++) {
                int ntg = (n0 >> 4) + nt0 + ntl;
                if (ntg >= NT_STAT) ntg = NT_STAT - 1;   // OOB cols: finite junk
                Bh[ntl] = *(const bf16x8*)(Ustat + ((size_t)ntg * 64 + lane) * 8);
                Bl[ntl] = *(const bf16x8*)(Ustat + (size_t)NT_STAT * 512 + ((size_t)ntg * 64 + lane) * 8);
            }
        }
        const u16* ab = (ks < 2) ? (AcwL + (size_t)ks * 4096) : wb2;
        #pragma unroll
        for (int mt = 0; mt < 4; mt++) {
            bf16x8 Ah = *(const bf16x8*)(ab + (size_t)mt * 512 + lane * 8);
            bf16x8 Al = *(const bf16x8*)(ab + (size_t)(4 + mt) * 512 + lane * 8);
            #pragma unroll
            for (int ntl = 0; ntl < 2; ntl++) {
                acc[mt][ntl] = __builtin_amdgcn_mfma_f32_16x16x32_bf16(Ah, Bh[ntl], acc[mt][ntl], 0, 0, 0);
                acc[mt][ntl] = __builtin_amdgcn_mfma_f32_16x16x32_bf16(Ah, Bl[ntl], acc[mt][ntl], 0, 0, 0);
                acc[mt][ntl] = __builtin_amdgcn_mfma_f32_16x16x32_bf16(Al, Bh[ntl], acc[mt][ntl], 0, 0, 0);
                acc[mt][ntl] = __builtin_amdgcn_mfma_f32_16x16x32_bf16(Al, Bl[ntl], acc[mt][ntl], 0, 0, 0);
            }
        }
    }

    // ---- epilogue: gelu + split + full-width fragment stores ----
    short4v hv[4][2], lv[4][2];
    #pragma unroll
    for (int ntl = 0; ntl < 2; ntl++) {
        int nt = nt0 + ntl;
        #pragma unroll
        for (int mt = 0; mt < 4; mt++) {
            #pragma unroll
            for (int j = 0; j < 4; j++) {
                float gv = gelu_f(acc[mt][ntl][j]);
                u16 h, lo;
                bf16split(gv, h, lo);
                hv[mt][ntl][j] = (short)h;
                lv[mt][ntl][j] = (short)lo;
            }
        }
        *(short8v*)(vfb + ((size_t)0 * 16 + nt) * 512 + lane * 8) = cat4(hv[0][ntl], hv[1][ntl]);
        *(short8v*)(vfb + ((size_t)1 * 16 + nt) * 512 + lane * 8) = cat4(lv[0][ntl], lv[1][ntl]);
        *(short8v*)(vfb + ((size_t)2 * 16 + nt) * 512 + lane * 8) = cat4(hv[2][ntl], hv[3][ntl]);
        *(short8v*)(vfb + ((size_t)3 * 16 + nt) * 512 + lane * 8) = cat4(lv[2][ntl], lv[3][ntl]);
    }

    dft_fused(packW + wv * 2048, racc, hv, lv, wv, lane, t, blk, n0,
              Tdft, Fpart + (size_t)b * fstride, atomicMode);
}

// LAST LAYER fused conv + gelu + projection: conv result never touches memory.
// Grid (32, NB): the blk=32 pad tile of v5 is unused by the projection.
__global__ __launch_bounds__(512, 4) void kconvp(const u16* __restrict__ Vf,
        const u16* __restrict__ AcwL, const u16* __restrict__ WfA2,
        const u16* __restrict__ Ustat, const u16* __restrict__ Aw1,
        const float* __restrict__ b1, const float* __restrict__ w2,
        const float* __restrict__ b2, float* __restrict__ out) {
    int t = threadIdx.x;
    int b = blockIdx.y;
    int blk = blockIdx.x;                 // 0..31, n < 8192 only
    int n0 = blk * 256;
    int lane = t & 63;
    int wv = __builtin_amdgcn_readfirstlane(t >> 6);
    const u16* vfb = Vf + ((size_t)b * NBLK + blk) * 32768;
    int nt0 = wv * 2;

    f32x4 acc[4][2];
    #pragma unroll
    for (int mt = 0; mt < 4; mt++)
        #pragma unroll
        for (int j = 0; j < 2; j++)
            acc[mt][j] = (f32x4){0.f, 0.f, 0.f, 0.f};

    const u16* wb2 = WfA2 + (size_t)b * 4096;
    #pragma unroll
    for (int ks = 0; ks < 3; ks++) {
        bf16x8 Bh[2], Bl[2];
        if (ks < 2) {
            #pragma unroll
            for (int ntl = 0; ntl < 2; ntl++) {
                Bh[ntl] = *(const bf16x8*)(vfb + (((size_t)ks * 2 + 0) * 16 + nt0 + ntl) * 512 + lane * 8);
                Bl[ntl] = *(const bf16x8*)(vfb + (((size_t)ks * 2 + 1) * 16 + nt0 + ntl) * 512 + lane * 8);
            }
        } else {
            #pragma unroll
            for (int ntl = 0; ntl < 2; ntl++) {
                int ntg = (n0 >> 4) + nt0 + ntl;     // < 512 always here
                Bh[ntl] = *(const bf16x8*)(Ustat + ((size_t)ntg * 64 + lane) * 8);
                Bl[ntl] = *(const bf16x8*)(Ustat + (size_t)NT_STAT * 512 + ((size_t)ntg * 64 + lane) * 8);
            }
        }
        const u16* ab = (ks < 2) ? (AcwL + (size_t)ks * 4096) : wb2;
        #pragma unroll
        for (int mt = 0; mt < 4; mt++) {
            bf16x8 Ah = *(const bf16x8*)(ab + (size_t)mt * 512 + lane * 8);
            bf16x8 Al = *(const bf16x8*)(ab + (size_t)(4 + mt) * 512 + lane * 8);
            #pragma unroll
            for (int ntl = 0; ntl < 2; ntl++) {
                acc[mt][ntl] = __builtin_amdgcn_mfma_f32_16x16x32_bf16(Ah, Bh[ntl], acc[mt][ntl], 0, 0, 0);
                acc[mt][ntl] = __builtin_amdgcn_mfma_f32_16x16x32_bf16(Ah, Bl[ntl], acc[mt][ntl], 0, 0, 0);
                acc[mt][ntl] = __builtin_amdgcn_mfma_f32_16x16x32_bf16(Al, Bh[ntl], acc[mt][ntl], 0, 0, 0);
                acc[mt][ntl] = __builtin_amdgcn_mfma_f32_16x16x32_bf16(Al, Bl[ntl], acc[mt][ntl], 0, 0, 0);
            }
        }
    }

    // ---- gelu + split directly into projection B-frags (register identity) ----
    bf16x8 Bph[2][2], Bpl[2][2];
    #pragma unroll
    for (int ntl = 0; ntl < 2; ntl++) {
        #pragma unroll
        for (int mt = 0; mt < 4; mt++) {
            #pragma unroll
            for (int j = 0; j < 4; j++) {
                float gv = gelu_f(acc[mt][ntl][j]);
                u16 h, lo;
                bf16split(gv, h, lo);
                Bph[mt >> 1][ntl][(mt & 1) * 4 + j] = (short)h;
                Bpl[mt >> 1][ntl][(mt & 1) * 4 + j] = (short)lo;
            }
        }
    }

    // ---- projection GEMM ----
    int r4 = (lane >> 4) << 2;
    f32x4 pacc[8][2];
    #pragma unroll
    for (int mt = 0; mt < 8; mt++) {
        #pragma unroll
        for (int j = 0; j < 4; j++) {
            float bs = b1[mt * 16 + r4 + j];
            pacc[mt][0][j] = bs;
            pacc[mt][1][j] = bs;
        }
    }
    #pragma unroll
    for (int ks = 0; ks < 2; ks++) {
        #pragma unroll
        for (int mt = 0; mt < 8; mt++) {
            bf16x8 Ah = *(const bf16x8*)(Aw1 + (((size_t)ks * 2 + 0) * 8 + mt) * 512 + lane * 8);
            bf16x8 Al = *(const bf16x8*)(Aw1 + (((size_t)ks * 2 + 1) * 8 + mt) * 512 + lane * 8);
            #pragma unroll
            for (int ntl = 0; ntl < 2; ntl++) {
                pacc[mt][ntl] = __builtin_amdgcn_mfma_f32_16x16x32_bf16(Ah, Bph[ks][ntl], pacc[mt][ntl], 0, 0, 0);
                pacc[mt][ntl] = __builtin_amdgcn_mfma_f32_16x16x32_bf16(Ah, Bpl[ks][ntl], pacc[mt][ntl], 0, 0, 0);
                pacc[mt][ntl] = __builtin_amdgcn_mfma_f32_16x16x32_bf16(Al, Bph[ks][ntl], pacc[mt][ntl], 0, 0, 0);
                pacc[mt][ntl] = __builtin_amdgcn_mfma_f32_16x16x32_bf16(Al, Bpl[ks][ntl], pacc[mt][ntl], 0, 0, 0);
            }
        }
    }

    float bb = b2[0];
    #pragma unroll
    for (int ntl = 0; ntl < 2; ntl++) {
        float p = 0.f;
        #pragma unroll
        for (int mt = 0; mt < 8; mt++) {
            p = fmaf(gelu_f(pacc[mt][ntl][0]), w2[mt * 16 + r4 + 0], p);
            p = fmaf(gelu_f(pacc[mt][ntl][1]), w2[mt * 16 + r4 + 1], p);
            p = fmaf(gelu_f(pacc[mt][ntl][2]), w2[mt * 16 + r4 + 2], p);
            p = fmaf(gelu_f(pacc[mt][ntl][3]), w2[mt * 16 + r4 + 3], p);
        }
        p += __shfl_xor(p, 16, 64);
        p += __shfl_xor(p, 32, 64);
        if (lane < 16) {
            int n = n0 + wv * 32 + ntl * 16 + lane;
            out[(size_t)b * 8192 + n] = p + bb;
        }
    }
}

extern "C" void kernel_launch(void* const* d_in, const int* in_sizes, int n_in,
                              void* d_out, int out_size, void* d_ws, size_t ws_size,
                              hipStream_t stream) {
    const float* x  = (const float*)d_in[0];
    const float* lw = (const float*)d_in[1];
    const float* lb = (const float*)d_in[2];
    const float* kr = (const float*)d_in[3];
    const float* ki = (const float*)d_in[4];
    const float* cw = (const float*)d_in[5];
    const float* cb = (const float*)d_in[6];
    const float* w1 = (const float*)d_in[7];
    const float* b1 = (const float*)d_in[8];
    const float* w2 = (const float*)d_in[9];
    const float* b2 = (const float*)d_in[10];
    float* out = (float*)d_out;

    // workspace: Vf 138.4 MB | Ustat 1.05 | Acw 0.08 | WfA2 0.5 | Tdft 1.05 |
    // Aw1 0.03 | Fpart f32: partial mode 17.3 MB (total ~158.5 MB) or atomic
    // fallback 0.5 MB (total ~141.7 MB).
    u16* wsu = (u16*)d_ws;
    size_t VFLEN = (size_t)NB * NBLK * 32768;
    u16* Vf     = wsu;
    u16* Ustat  = Vf + VFLEN;
    u16* AcwBuf = Ustat + (size_t)2 * NT_STAT * 512;
    u16* WfA2   = AcwBuf + (size_t)NL * 8192;
    u16* Tdft   = WfA2 + (size_t)NB * 4096;
    u16* Aw1    = Tdft + (size_t)NSTEPS * 2048;
    u16* fend   = Aw1 + (size_t)16384;
    float* Fpart = (float*)fend;
    size_t base_bytes = (size_t)(fend - wsu) * sizeof(u16);
    size_t need_partial = base_bytes + (size_t)NB * NBLK * 2048 * sizeof(float);
    int atomicMode = (ws_size >= need_partial) ? 0 : 1;
    int fstride = atomicMode ? 2048 : (NBLK * 2048);
    int nblk = atomicMode ? 1 : NBLK;

    kstat<<<dim3(NT_STAT), 256, 0, stream>>>(Ustat);
    kdtab<<<dim3(NSTEPS), 256, 0, stream>>>(Tdft);
    kprep<<<dim3(NL), 256, 0, stream>>>(cw, AcwBuf);
    kprep2<<<dim3(1), 256, 0, stream>>>(w1, Aw1);

    if (atomicMode)
        hipMemsetAsync(Fpart, 0, (size_t)NB * 2048 * sizeof(float), stream);
    klift2<<<dim3(NBLK, NB), 512, 0, stream>>>(x, lw, lb, Vf, Tdft, Fpart,
                                               fstride, atomicMode);

    for (int l = 0; l < NL; l++) {
        kmix<<<dim3(NB, 4), 256, 0, stream>>>(Fpart, kr, ki, cb, WfA2, l,
                                              nblk, fstride);
        if (l < NL - 1) {
            if (atomicMode)
                hipMemsetAsync(Fpart, 0, (size_t)NB * 2048 * sizeof(float), stream);
            kconv<<<dim3(NBLK, NB), 512, 0, stream>>>(Vf,
                    AcwBuf + (size_t)l * 8192, WfA2, Ustat, Tdft, Fpart,
                    fstride, atomicMode);
        } else {
            kconvp<<<dim3(32, NB), 512, 0, stream>>>(Vf,
                    AcwBuf + (size_t)l * 8192, WfA2, Ustat, Aw1,
                    b1, w2, b2, out);
        }
    }
}

// Round 8
// 1278.023 us; speedup vs baseline: 1.1539x; 1.1539x over previous
//
#include <hip/hip_runtime.h>
#include <math.h>

// FNO1d: B=64, N=8192, F_IN=2, W=64, L=5, M=16, PAD=9 -> NLEN=8201
#define NLEN 8201
#define NB 64
#define W 64
#define M 16
#define NL 5
#define TWO_PI 6.283185307179586476925286766559
#define NT_STAT 514    // static B-frag n-tiles (n < 8224); OOB tiles clamp there
#define NSTEPS 257     // DFT twiddle A-frag K-steps of 32 (covers n < 8224)
#define NBLK 33        // 33 x 256 = 8448 logical cols (8201 valid, rest junk-safe)

typedef unsigned short u16;
typedef __attribute__((ext_vector_type(8))) short bf16x8;   // MFMA A/B frag (4 VGPR)
typedef __attribute__((ext_vector_type(4))) float f32x4;    // MFMA C/D frag
typedef __attribute__((ext_vector_type(4))) short short4v;
typedef __attribute__((ext_vector_type(8))) short short8v;

// ---- bf16 split-precision helpers (x = hi + lo, both RN bf16) ----
// NOTE: the lo(A)*lo(B) MFMA term (~2^-16 relative) is DROPPED everywhere:
// error ~2e-5 absolute, 25x below the measured absmax. 3 MFMA per pair.
__device__ __forceinline__ u16 bf16rn(float x) {
    unsigned u = __float_as_uint(x);
    unsigned r = (u + 0x7fffu + ((u >> 16) & 1u)) >> 16;
    return (u16)r;
}
__device__ __forceinline__ float bf16tof(u16 h) {
    return __uint_as_float(((unsigned)h) << 16);
}
__device__ __forceinline__ void bf16split(float x, u16& h, u16& lo) {
    h = bf16rn(x);
    lo = bf16rn(x - bf16tof(h));
}

__device__ __forceinline__ short8v cat4(short4v a, short4v b) {
    short8v r;
    r[0] = a[0]; r[1] = a[1]; r[2] = a[2]; r[3] = a[3];
    r[4] = b[0]; r[5] = b[1]; r[6] = b[2]; r[7] = b[3];
    return r;
}

__device__ __forceinline__ void atomicAddF(float* p, float v) {
    __hip_atomic_fetch_add(p, v, __ATOMIC_RELAXED, __HIP_MEMORY_SCOPE_AGENT);
}

// Both MFMA operand sides always use the SAME (lane>>4, e) -> kk bijection, so
// the hardware's exact within-K ordering cancels out of every contraction.
//   main GEMM:     kk(g,e) = g*4 + (e&3) + 16*(e>>2)
//   DFT epilogue:  nloc(g,e) = g*8 + e
//
// v lives in GLOBAL memory pre-fragmented ("Vf"): per (b, blk) a 64 KB tile
// Vf[plane(4)=ks*2+hl][nt(16)][lane(64)][e(8)] of u16. Wave wv's GEMM B-frags
// are the nt = wv*2+ntl slices -> DISJOINT per wave -> loaded straight from
// global to registers (coalesced 16B/lane). The format is an IDENTITY between
// producer epilogue registers and consumer B-frags (enables the last-layer
// conv+projection fusion fully in registers).
//
// R7 lesson (scratch-spill disaster): never pass the live hv/lv fragment
// arrays through a function boundary, and no aggressive min-waves bounds.
// All DFT-tail code is INLINED in klift2/kconv below.

// Branchless gelu: A&S 7.1.26 erf (|err| <= 1.5e-7), rcp+exp fast paths.
__device__ __forceinline__ float gelu_f(float x) {
    float s = x * 0.70710678118654752f;
    float a = fabsf(s);
    float t = __builtin_amdgcn_rcpf(fmaf(0.3275911f, a, 1.0f));
    float p = fmaf(1.061405429f, t, -1.453152027f);
    p = fmaf(p, t, 1.421413741f);
    p = fmaf(p, t, -0.284496736f);
    p = fmaf(p, t, 0.254829592f);
    p = p * t;
    float e = __expf(-a * a);
    float er = copysignf(fmaf(-p, e, 1.0f), s);
    float h = 0.5f * x;
    return fmaf(h, er, h);
}

// Static B-frags for main-GEMM ks=2 (U rows 64..95 = [cos1..15|sin1..15|1|0]).
__global__ __launch_bounds__(256) void kstat(u16* __restrict__ Ustat) {
    int nt = blockIdx.x;             // 0..NT_STAT-1
    int t = threadIdx.x;
    for (int s = t; s < 512; s += 256) {
        int lane = s >> 3, e = s & 7;
        int kk = ((lane >> 4) << 2) + (e & 3) + ((e >> 2) << 4);
        int r = 64 + kk;
        int n = nt * 16 + (lane & 15);
        float val;
        if (r < 94) {
            int k = (r < 79) ? (r - 63) : (r - 78);
            long long mm = ((long long)k * (long long)n) % NLEN;
            double th = (TWO_PI / (double)NLEN) * (double)mm;
            double sv, cv;
            sincos(th, &sv, &cv);
            val = (float)((r < 79) ? cv : sv);
        } else {
            val = (r == 94) ? 1.0f : 0.0f;
        }
        u16 h, lo;
        bf16split(val, h, lo);
        size_t base = ((size_t)nt * 64 + lane) * 8 + e;
        Ustat[base] = h;
        Ustat[(size_t)NT_STAT * 512 + base] = lo;
    }
}

// Twiddle A-frags for the fused DFT: Tdft[nstep][kcT(2)][hl(2)][lane][e].
// A[m=kc][n]: kc<16 -> cos(2pi*kc*n/NLEN); kc>=16 -> -sin(2pi*(kc-16)*n/NLEN).
__global__ __launch_bounds__(256) void kdtab(u16* __restrict__ Tdft) {
    int nstep = blockIdx.x;
    int t = threadIdx.x;
    for (int s = t; s < 1024; s += 256) {     // kcT(2) x lane(64) x e(8)
        int e = s & 7, lane = (s >> 3) & 63, kcT = s >> 9;
        int kc = kcT * 16 + (lane & 15);
        int n = nstep * 32 + ((lane >> 4) << 3) + e;
        int k = kc & 15;
        long long m = ((long long)k * (long long)n) % NLEN;
        double th = (TWO_PI / (double)NLEN) * (double)m;
        double sv, cv;
        sincos(th, &sv, &cv);
        float val = (kc < 16) ? (float)cv : (float)(-sv);
        u16 h, lo;
        bf16split(val, h, lo);
        size_t base = (((size_t)nstep * 2 + kcT) * 2) * 512 + lane * 8 + e;
        Tdft[base] = h;
        Tdft[base + 512] = lo;
    }
}

// Pack cw (all 5 layers) into A-frags: AcwBuf[l][ks(2)][hl(2)][mt(4)][lane][e].
__global__ __launch_bounds__(256) void kprep(const float* __restrict__ cw,
                                             u16* __restrict__ AcwBuf) {
    int l = blockIdx.x;
    int t = threadIdx.x;
    const float* cwl = cw + (size_t)l * W * W;
    u16* ob = AcwBuf + (size_t)l * 8192;
    for (int s = t; s < 4096; s += 256) {
        int e = s & 7, lane = (s >> 3) & 63, mt = (s >> 9) & 3, ks = s >> 11;
        int kk = ((lane >> 4) << 2) + (e & 3) + ((e >> 2) << 4);
        int k = ks * 32 + kk;
        int o = mt * 16 + (lane & 15);
        u16 h, lo;
        bf16split(cwl[o * 64 + k], h, lo);
        ob[(((size_t)ks * 2 + 0) * 4 + mt) * 512 + lane * 8 + e] = h;
        ob[(((size_t)ks * 2 + 1) * 4 + mt) * 512 + lane * 8 + e] = lo;
    }
}

// Pack w1 (64k x 128h) into A-frags: Aw1[ks(2)][hl(2)][mt(8)][lane][e].
__global__ __launch_bounds__(256) void kprep2(const float* __restrict__ w1,
                                              u16* __restrict__ Aw1) {
    int t = threadIdx.x;
    for (int s = t; s < 8192; s += 256) {    // ks(2) x mt(8) x lane(64) x e(8)
        int e = s & 7, lane = (s >> 3) & 63, mt = (s >> 9) & 7, ks = s >> 12;
        int kk = ((lane >> 4) << 2) + (e & 3) + ((e >> 2) << 4);
        int k = ks * 32 + kk;
        int h = mt * 16 + (lane & 15);
        u16 hh, lo;
        bf16split(w1[k * 128 + h], hh, lo);
        Aw1[(((size_t)ks * 2 + 0) * 8 + mt) * 512 + lane * 8 + e] = hh;
        Aw1[(((size_t)ks * 2 + 1) * 8 + mt) * 512 + lane * 8 + e] = lo;
    }
}

// INLINE DFT tail used by klift2/kconv (kept as a macro-free code pattern,
// duplicated in both kernels; see R7 lesson above).
// packw: 4 KB wave-private region; racc: 8 KB shared accumulator (pre-zeroed
// + barriered). Two o-halves stream through packw; per-wave DS ops are
// in-order so the half-1 overwrite is safe.

// Fused lift + forward-DFT.
__global__ __launch_bounds__(512, 4) void klift2(const float* __restrict__ x,
        const float* __restrict__ lw, const float* __restrict__ lb,
        u16* __restrict__ Vf, const u16* __restrict__ Tdft,
        float* __restrict__ Fpart, int fstride, int atomicMode) {
    __shared__ __align__(16) u16 packW[8 * 2048];   // 32 KB
    __shared__ __align__(16) float racc[2048];      // 8 KB
    int t = threadIdx.x;
    int b = blockIdx.y;
    int blk = blockIdx.x;
    int lane = t & 63;
    int wv = __builtin_amdgcn_readfirstlane(t >> 6);
    int r4 = (lane >> 4) << 2;
    int g = lane >> 4;
    u16* vfb = Vf + ((size_t)b * NBLK + blk) * 32768;
    int n0 = blk * 256;

    *(float4*)(racc + t * 4) = (float4){0.f, 0.f, 0.f, 0.f};
    __syncthreads();

    short4v hv[4][2], lv[4][2];
    #pragma unroll
    for (int ntl = 0; ntl < 2; ntl++) {
        int nt = wv * 2 + ntl;
        int n = n0 + nt * 16 + (lane & 15);
        float x0 = 0.f, x1 = 0.f;
        bool in = (n < 8192);
        if (in) {
            const float* xp = x + ((size_t)b * 8192 + n) * 2;
            x0 = xp[0]; x1 = xp[1];
        }
        #pragma unroll
        for (int mt = 0; mt < 4; mt++) {
            #pragma unroll
            for (int j = 0; j < 4; j++) {
                int o = mt * 16 + r4 + j;
                float val = in ? fmaf(x0, lw[o], fmaf(x1, lw[64 + o], lb[o])) : 0.f;
                u16 h, lo;
                bf16split(val, h, lo);
                hv[mt][ntl][j] = (short)h;
                lv[mt][ntl][j] = (short)lo;
            }
        }
        *(short8v*)(vfb + ((size_t)0 * 16 + nt) * 512 + lane * 8) = cat4(hv[0][ntl], hv[1][ntl]);
        *(short8v*)(vfb + ((size_t)1 * 16 + nt) * 512 + lane * 8) = cat4(lv[0][ntl], lv[1][ntl]);
        *(short8v*)(vfb + ((size_t)2 * 16 + nt) * 512 + lane * 8) = cat4(hv[2][ntl], hv[3][ntl]);
        *(short8v*)(vfb + ((size_t)3 * 16 + nt) * 512 + lane * 8) = cat4(lv[2][ntl], lv[3][ntl]);
    }

    // ---- inline DFT tail ----
    {
        u16* packw = packW + wv * 2048;
        int nstep = blk * 8 + wv;
        if (nstep > NSTEPS - 1) nstep = NSTEPS - 1;   // OOB waves have zero B
        const u16* at = Tdft + (size_t)nstep * 2048;
        bf16x8 Th0 = *(const bf16x8*)(at + lane * 8);
        bf16x8 Tl0 = *(const bf16x8*)(at + 512 + lane * 8);
        bf16x8 Th1 = *(const bf16x8*)(at + 1024 + lane * 8);
        bf16x8 Tl1 = *(const bf16x8*)(at + 1536 + lane * 8);
        f32x4 dacc[2][4];
        #pragma unroll
        for (int kt = 0; kt < 2; kt++)
            #pragma unroll
            for (int ot = 0; ot < 4; ot++) dacc[kt][ot] = (f32x4){0.f, 0.f, 0.f, 0.f};
        #pragma unroll
        for (int half = 0; half < 2; half++) {
            #pragma unroll
            for (int ntl = 0; ntl < 2; ntl++) {
                int nl = ntl * 16 + (lane & 15);
                bool ok = (n0 + wv * 32 + nl) <= 8200;
                #pragma unroll
                for (int mtl = 0; mtl < 2; mtl++) {
                    #pragma unroll
                    for (int j = 0; j < 4; j++) {
                        int op = mtl * 16 + r4 + j;
                        u16 h  = ok ? (u16)hv[half * 2 + mtl][ntl][j] : (u16)0;
                        u16 lo = ok ? (u16)lv[half * 2 + mtl][ntl][j] : (u16)0;
                        int raw = op * 128 + nl * 2;
                        int swz = (op & 7) << 4;
                        packw[(raw ^ swz) >> 1] = h;
                        packw[((raw + 64) ^ swz) >> 1] = lo;
                    }
                }
            }
            #pragma unroll
            for (int otl = 0; otl < 2; otl++) {
                int op = otl * 16 + (lane & 15);
                int swz = (op & 7) << 4;
                bf16x8 Bh = *(const bf16x8*)(packw + (((op * 128 + g * 16) ^ swz) >> 1));
                bf16x8 Bl = *(const bf16x8*)(packw + (((op * 128 + 64 + g * 16) ^ swz) >> 1));
                int ot = half * 2 + otl;
                dacc[0][ot] = __builtin_amdgcn_mfma_f32_16x16x32_bf16(Th0, Bh, dacc[0][ot], 0, 0, 0);
                dacc[0][ot] = __builtin_amdgcn_mfma_f32_16x16x32_bf16(Th0, Bl, dacc[0][ot], 0, 0, 0);
                dacc[0][ot] = __builtin_amdgcn_mfma_f32_16x16x32_bf16(Tl0, Bh, dacc[0][ot], 0, 0, 0);
                dacc[1][ot] = __builtin_amdgcn_mfma_f32_16x16x32_bf16(Th1, Bh, dacc[1][ot], 0, 0, 0);
                dacc[1][ot] = __builtin_amdgcn_mfma_f32_16x16x32_bf16(Th1, Bl, dacc[1][ot], 0, 0, 0);
                dacc[1][ot] = __builtin_amdgcn_mfma_f32_16x16x32_bf16(Tl1, Bh, dacc[1][ot], 0, 0, 0);
            }
        }
        #pragma unroll
        for (int kt = 0; kt < 2; kt++)
            #pragma unroll
            for (int ot = 0; ot < 4; ot++) {
                int oo = ot * 16 + (lane & 15);
                int kcb = kt * 16 + g * 4;
                atomicAdd(&racc[(kcb + 0) * 64 + oo], dacc[kt][ot][0]);
                atomicAdd(&racc[(kcb + 1) * 64 + oo], dacc[kt][ot][1]);
                atomicAdd(&racc[(kcb + 2) * 64 + oo], dacc[kt][ot][2]);
                atomicAdd(&racc[(kcb + 3) * 64 + oo], dacc[kt][ot][3]);
            }
        __syncthreads();
        {
            float* FpB = Fpart + (size_t)b * fstride;
            int idx = t * 4;
            float4 s = *(const float4*)(racc + idx);
            if (atomicMode) {
                atomicAddF(FpB + idx + 0, s.x);
                atomicAddF(FpB + idx + 1, s.y);
                atomicAddF(FpB + idx + 2, s.z);
                atomicAddF(FpB + idx + 3, s.w);
            } else {
                *(float4*)(FpB + (size_t)blk * 2048 + idx) = s;
            }
        }
    }
}

// Write one W-matrix value (row 64+kk, col o) into per-b ks2 A-frags (hi+lo).
__device__ __forceinline__ void wfrag(u16* wb2, int mt, int kk, int ol, float val) {
    int lane = ol + (((kk & 15) >> 2) << 4);
    int e = (kk & 3) + ((kk >> 4) << 2);
    u16 h, lo;
    bf16split(val, h, lo);
    wb2[(size_t)mt * 512 + lane * 8 + e] = h;
    wb2[(size_t)(4 + mt) * 512 + lane * 8 + e] = lo;
}

// Mode mix. Phase 1: reduce Fpart[b][0..nblk) into LDS Fs[8][64]. Phase 2:
// P = F*kern, emit spectral A-frags WfA2[b].
__global__ __launch_bounds__(256) void kmix(const float* __restrict__ Fpart,
        const float* __restrict__ kr, const float* __restrict__ ki,
        const float* __restrict__ cb, u16* __restrict__ WfA2, int l,
        int nblk, int fstride) {
    int b = blockIdx.x, kg = blockIdx.y;
    int t = threadIdx.x;
    int o = t & 63, ii = t >> 6;
    __shared__ float Fs[8][64];
    {
        const float* fp = Fpart + (size_t)b * fstride;
        int r0 = t >> 6, oo = t & 63;
        int kc0 = kg * 4 + r0;          // cos rows (Re)
        int kc1 = 16 + kg * 4 + r0;     // sin rows (Im)
        float s0 = 0.f, s1 = 0.f, s2 = 0.f, s3 = 0.f;
        int blk = 0;
        for (; blk + 2 <= nblk; blk += 2) {
            s0 += fp[(size_t)blk * 2048 + kc0 * 64 + oo];
            s1 += fp[(size_t)(blk + 1) * 2048 + kc0 * 64 + oo];
            s2 += fp[(size_t)blk * 2048 + kc1 * 64 + oo];
            s3 += fp[(size_t)(blk + 1) * 2048 + kc1 * 64 + oo];
        }
        if (blk < nblk) {
            s0 += fp[(size_t)blk * 2048 + kc0 * 64 + oo];
            s2 += fp[(size_t)blk * 2048 + kc1 * 64 + oo];
        }
        Fs[r0][oo] = s0 + s1;
        Fs[4 + r0][oo] = s2 + s3;
    }
    __syncthreads();

    const float* krl = kr + (size_t)l * W * W * M;
    const float* kil = ki + (size_t)l * W * W * M;
    float pr[4] = {0.f, 0.f, 0.f, 0.f}, pi[4] = {0.f, 0.f, 0.f, 0.f};
    for (int i = ii * 16; i < ii * 16 + 16; i++) {
        float4 kr4 = *(const float4*)(krl + ((size_t)i * W + o) * M + kg * 4);
        float4 ki4 = *(const float4*)(kil + ((size_t)i * W + o) * M + kg * 4);
        float re0 = Fs[0][i], im0 = Fs[4][i];
        float re1 = Fs[1][i], im1 = Fs[5][i];
        float re2 = Fs[2][i], im2 = Fs[6][i];
        float re3 = Fs[3][i], im3 = Fs[7][i];
        pr[0] += re0 * kr4.x - im0 * ki4.x;  pi[0] += re0 * ki4.x + im0 * kr4.x;
        pr[1] += re1 * kr4.y - im1 * ki4.y;  pi[1] += re1 * ki4.y + im1 * kr4.y;
        pr[2] += re2 * kr4.z - im2 * ki4.z;  pi[2] += re2 * ki4.z + im2 * kr4.z;
        pr[3] += re3 * kr4.w - im3 * ki4.w;  pi[3] += re3 * ki4.w + im3 * kr4.w;
    }
    __shared__ float red[4][64][8];
    #pragma unroll
    for (int c = 0; c < 4; c++) {
        red[ii][o][2 * c]     = pr[c];
        red[ii][o][2 * c + 1] = pi[c];
    }
    __syncthreads();
    if (ii == 0) {
        u16* wb2 = WfA2 + (size_t)b * 4096;
        int mt = o >> 4, ol = o & 15;
        #pragma unroll
        for (int c = 0; c < 4; c++) {
            int k = kg * 4 + c;
            float sr = red[0][o][2 * c] + red[1][o][2 * c] + red[2][o][2 * c] + red[3][o][2 * c];
            float si = red[0][o][2 * c + 1] + red[1][o][2 * c + 1] + red[2][o][2 * c + 1] + red[3][o][2 * c + 1];
            if (k == 0) {
                wfrag(wb2, mt, 30, ol, cb[l * W + o] + sr * (1.0f / (float)NLEN));
                wfrag(wb2, mt, 31, ol, 0.0f);
            } else {
                wfrag(wb2, mt, k - 1,  ol, sr * (2.0f / (float)NLEN));
                wfrag(wb2, mt, 14 + k, ol, -si * (2.0f / (float)NLEN));
            }
        }
    }
}

// Fused conv + inverse transform + gelu via bf16-split MFMA on fragment-format
// Vf, IN-PLACE, plus fused forward-DFT of the output (layers 0..3).
__global__ __launch_bounds__(512, 4) void kconv(u16* __restrict__ Vf,
        const u16* __restrict__ AcwL, const u16* __restrict__ WfA2,
        const u16* __restrict__ Ustat, const u16* __restrict__ Tdft,
        float* __restrict__ Fpart, int fstride, int atomicMode) {
    __shared__ __align__(16) u16 packW[8 * 2048];   // 32 KB
    __shared__ __align__(16) float racc[2048];      // 8 KB
    int t = threadIdx.x;
    int b = blockIdx.y;
    int blk = blockIdx.x;
    int n0 = blk * 256;
    int lane = t & 63;
    int wv = __builtin_amdgcn_readfirstlane(t >> 6);       // 0..7
    int g = lane >> 4;
    int r4 = g << 2;
    u16* vfb = Vf + ((size_t)b * NBLK + blk) * 32768;
    int nt0 = wv * 2;

    *(float4*)(racc + t * 4) = (float4){0.f, 0.f, 0.f, 0.f};
    __syncthreads();

    // ---- direct B-frag loads (upfront, all in flight) ----
    bf16x8 Bh[3][2], Bl[3][2];
    #pragma unroll
    for (int ks = 0; ks < 2; ks++)
        #pragma unroll
        for (int ntl = 0; ntl < 2; ntl++) {
            Bh[ks][ntl] = *(const bf16x8*)(vfb + (((size_t)ks * 2 + 0) * 16 + nt0 + ntl) * 512 + lane * 8);
            Bl[ks][ntl] = *(const bf16x8*)(vfb + (((size_t)ks * 2 + 1) * 16 + nt0 + ntl) * 512 + lane * 8);
        }
    #pragma unroll
    for (int ntl = 0; ntl < 2; ntl++) {
        int ntg = (n0 >> 4) + nt0 + ntl;
        if (ntg >= NT_STAT) ntg = NT_STAT - 1;   // OOB cols: finite junk
        Bh[2][ntl] = *(const bf16x8*)(Ustat + ((size_t)ntg * 64 + lane) * 8);
        Bl[2][ntl] = *(const bf16x8*)(Ustat + (size_t)NT_STAT * 512 + ((size_t)ntg * 64 + lane) * 8);
    }

    f32x4 acc[4][2];
    #pragma unroll
    for (int mt = 0; mt < 4; mt++)
        #pragma unroll
        for (int j = 0; j < 2; j++)
            acc[mt][j] = (f32x4){0.f, 0.f, 0.f, 0.f};

    const u16* wb2 = WfA2 + (size_t)b * 4096;
    #pragma unroll
    for (int ks = 0; ks < 3; ks++) {
        const u16* ab = (ks < 2) ? (AcwL + (size_t)ks * 4096) : wb2;
        #pragma unroll
        for (int mt = 0; mt < 4; mt++) {
            bf16x8 Ah = *(const bf16x8*)(ab + (size_t)mt * 512 + lane * 8);
            bf16x8 Al = *(const bf16x8*)(ab + (size_t)(4 + mt) * 512 + lane * 8);
            #pragma unroll
            for (int ntl = 0; ntl < 2; ntl++) {
                acc[mt][ntl] = __builtin_amdgcn_mfma_f32_16x16x32_bf16(Ah, Bh[ks][ntl], acc[mt][ntl], 0, 0, 0);
                acc[mt][ntl] = __builtin_amdgcn_mfma_f32_16x16x32_bf16(Ah, Bl[ks][ntl], acc[mt][ntl], 0, 0, 0);
                acc[mt][ntl] = __builtin_amdgcn_mfma_f32_16x16x32_bf16(Al, Bh[ks][ntl], acc[mt][ntl], 0, 0, 0);
            }
        }
    }

    // ---- epilogue: gelu + split + full-width fragment stores ----
    short4v hv[4][2], lv[4][2];
    #pragma unroll
    for (int ntl = 0; ntl < 2; ntl++) {
        int nt = nt0 + ntl;
        #pragma unroll
        for (int mt = 0; mt < 4; mt++) {
            #pragma unroll
            for (int j = 0; j < 4; j++) {
                float gv = gelu_f(acc[mt][ntl][j]);
                u16 h, lo;
                bf16split(gv, h, lo);
                hv[mt][ntl][j] = (short)h;
                lv[mt][ntl][j] = (short)lo;
            }
        }
        *(short8v*)(vfb + ((size_t)0 * 16 + nt) * 512 + lane * 8) = cat4(hv[0][ntl], hv[1][ntl]);
        *(short8v*)(vfb + ((size_t)1 * 16 + nt) * 512 + lane * 8) = cat4(lv[0][ntl], lv[1][ntl]);
        *(short8v*)(vfb + ((size_t)2 * 16 + nt) * 512 + lane * 8) = cat4(hv[2][ntl], hv[3][ntl]);
        *(short8v*)(vfb + ((size_t)3 * 16 + nt) * 512 + lane * 8) = cat4(lv[2][ntl], lv[3][ntl]);
    }

    // ---- inline DFT tail (identical pattern to klift2) ----
    {
        u16* packw = packW + wv * 2048;
        int nstep = blk * 8 + wv;
        if (nstep > NSTEPS - 1) nstep = NSTEPS - 1;
        const u16* at = Tdft + (size_t)nstep * 2048;
        bf16x8 Th0 = *(const bf16x8*)(at + lane * 8);
        bf16x8 Tl0 = *(const bf16x8*)(at + 512 + lane * 8);
        bf16x8 Th1 = *(const bf16x8*)(at + 1024 + lane * 8);
        bf16x8 Tl1 = *(const bf16x8*)(at + 1536 + lane * 8);
        f32x4 dacc[2][4];
        #pragma unroll
        for (int kt = 0; kt < 2; kt++)
            #pragma unroll
            for (int ot = 0; ot < 4; ot++) dacc[kt][ot] = (f32x4){0.f, 0.f, 0.f, 0.f};
        #pragma unroll
        for (int half = 0; half < 2; half++) {
            #pragma unroll
            for (int ntl = 0; ntl < 2; ntl++) {
                int nl = ntl * 16 + (lane & 15);
                bool ok = (n0 + wv * 32 + nl) <= 8200;
                #pragma unroll
                for (int mtl = 0; mtl < 2; mtl++) {
                    #pragma unroll
                    for (int j = 0; j < 4; j++) {
                        int op = mtl * 16 + r4 + j;
                        u16 h  = ok ? (u16)hv[half * 2 + mtl][ntl][j] : (u16)0;
                        u16 lo = ok ? (u16)lv[half * 2 + mtl][ntl][j] : (u16)0;
                        int raw = op * 128 + nl * 2;
                        int swz = (op & 7) << 4;
                        packw[(raw ^ swz) >> 1] = h;
                        packw[((raw + 64) ^ swz) >> 1] = lo;
                    }
                }
            }
            #pragma unroll
            for (int otl = 0; otl < 2; otl++) {
                int op = otl * 16 + (lane & 15);
                int swz = (op & 7) << 4;
                bf16x8 Bph = *(const bf16x8*)(packw + (((op * 128 + g * 16) ^ swz) >> 1));
                bf16x8 Bpl = *(const bf16x8*)(packw + (((op * 128 + 64 + g * 16) ^ swz) >> 1));
                int ot = half * 2 + otl;
                dacc[0][ot] = __builtin_amdgcn_mfma_f32_16x16x32_bf16(Th0, Bph, dacc[0][ot], 0, 0, 0);
                dacc[0][ot] = __builtin_amdgcn_mfma_f32_16x16x32_bf16(Th0, Bpl, dacc[0][ot], 0, 0, 0);
                dacc[0][ot] = __builtin_amdgcn_mfma_f32_16x16x32_bf16(Tl0, Bph, dacc[0][ot], 0, 0, 0);
                dacc[1][ot] = __builtin_amdgcn_mfma_f32_16x16x32_bf16(Th1, Bph, dacc[1][ot], 0, 0, 0);
                dacc[1][ot] = __builtin_amdgcn_mfma_f32_16x16x32_bf16(Th1, Bpl, dacc[1][ot], 0, 0, 0);
                dacc[1][ot] = __builtin_amdgcn_mfma_f32_16x16x32_bf16(Tl1, Bph, dacc[1][ot], 0, 0, 0);
            }
        }
        #pragma unroll
        for (int kt = 0; kt < 2; kt++)
            #pragma unroll
            for (int ot = 0; ot < 4; ot++) {
                int oo = ot * 16 + (lane & 15);
                int kcb = kt * 16 + g * 4;
                atomicAdd(&racc[(kcb + 0) * 64 + oo], dacc[kt][ot][0]);
                atomicAdd(&racc[(kcb + 1) * 64 + oo], dacc[kt][ot][1]);
                atomicAdd(&racc[(kcb + 2) * 64 + oo], dacc[kt][ot][2]);
                atomicAdd(&racc[(kcb + 3) * 64 + oo], dacc[kt][ot][3]);
            }
        __syncthreads();
        {
            float* FpB = Fpart + (size_t)b * fstride;
            int idx = t * 4;
            float4 s = *(const float4*)(racc + idx);
            if (atomicMode) {
                atomicAddF(FpB + idx + 0, s.x);
                atomicAddF(FpB + idx + 1, s.y);
                atomicAddF(FpB + idx + 2, s.z);
                atomicAddF(FpB + idx + 3, s.w);
            } else {
                *(float4*)(FpB + (size_t)blk * 2048 + idx) = s;
            }
        }
    }
}

// LAST LAYER fused conv + gelu + projection: conv result never touches memory.
// Grid (32, NB): the blk=32 pad tile of v5 is unused by the projection.
__global__ __launch_bounds__(512, 3) void kconvp(const u16* __restrict__ Vf,
        const u16* __restrict__ AcwL, const u16* __restrict__ WfA2,
        const u16* __restrict__ Ustat, const u16* __restrict__ Aw1,
        const float* __restrict__ b1, const float* __restrict__ w2,
        const float* __restrict__ b2, float* __restrict__ out) {
    int t = threadIdx.x;
    int b = blockIdx.y;
    int blk = blockIdx.x;                 // 0..31, n < 8192 only
    int n0 = blk * 256;
    int lane = t & 63;
    int wv = __builtin_amdgcn_readfirstlane(t >> 6);
    const u16* vfb = Vf + ((size_t)b * NBLK + blk) * 32768;
    int nt0 = wv * 2;

    // ---- conv B-frag loads ----
    bf16x8 Bh[3][2], Bl[3][2];
    #pragma unroll
    for (int ks = 0; ks < 2; ks++)
        #pragma unroll
        for (int ntl = 0; ntl < 2; ntl++) {
            Bh[ks][ntl] = *(const bf16x8*)(vfb + (((size_t)ks * 2 + 0) * 16 + nt0 + ntl) * 512 + lane * 8);
            Bl[ks][ntl] = *(const bf16x8*)(vfb + (((size_t)ks * 2 + 1) * 16 + nt0 + ntl) * 512 + lane * 8);
        }
    #pragma unroll
    for (int ntl = 0; ntl < 2; ntl++) {
        int ntg = (n0 >> 4) + nt0 + ntl;             // < 512 always here
        Bh[2][ntl] = *(const bf16x8*)(Ustat + ((size_t)ntg * 64 + lane) * 8);
        Bl[2][ntl] = *(const bf16x8*)(Ustat + (size_t)NT_STAT * 512 + ((size_t)ntg * 64 + lane) * 8);
    }

    f32x4 acc[4][2];
    #pragma unroll
    for (int mt = 0; mt < 4; mt++)
        #pragma unroll
        for (int j = 0; j < 2; j++)
            acc[mt][j] = (f32x4){0.f, 0.f, 0.f, 0.f};

    const u16* wb2 = WfA2 + (size_t)b * 4096;
    #pragma unroll
    for (int ks = 0; ks < 3; ks++) {
        const u16* ab = (ks < 2) ? (AcwL + (size_t)ks * 4096) : wb2;
        #pragma unroll
        for (int mt = 0; mt < 4; mt++) {
            bf16x8 Ah = *(const bf16x8*)(ab + (size_t)mt * 512 + lane * 8);
            bf16x8 Al = *(const bf16x8*)(ab + (size_t)(4 + mt) * 512 + lane * 8);
            #pragma unroll
            for (int ntl = 0; ntl < 2; ntl++) {
                acc[mt][ntl] = __builtin_amdgcn_mfma_f32_16x16x32_bf16(Ah, Bh[ks][ntl], acc[mt][ntl], 0, 0, 0);
                acc[mt][ntl] = __builtin_amdgcn_mfma_f32_16x16x32_bf16(Ah, Bl[ks][ntl], acc[mt][ntl], 0, 0, 0);
                acc[mt][ntl] = __builtin_amdgcn_mfma_f32_16x16x32_bf16(Al, Bh[ks][ntl], acc[mt][ntl], 0, 0, 0);
            }
        }
    }

    // ---- gelu + split directly into projection B-frags (register identity) ----
    bf16x8 Bph[2][2], Bpl[2][2];
    int r4 = (lane >> 4) << 2;
    #pragma unroll
    for (int ntl = 0; ntl < 2; ntl++) {
        #pragma unroll
        for (int mt = 0; mt < 4; mt++) {
            #pragma unroll
            for (int j = 0; j < 4; j++) {
                float gv = gelu_f(acc[mt][ntl][j]);
                u16 h, lo;
                bf16split(gv, h, lo);
                Bph[mt >> 1][ntl][(mt & 1) * 4 + j] = (short)h;
                Bpl[mt >> 1][ntl][(mt & 1) * 4 + j] = (short)lo;
            }
        }
    }

    // ---- projection GEMM ----
    f32x4 pacc[8][2];
    #pragma unroll
    for (int mt = 0; mt < 8; mt++) {
        #pragma unroll
        for (int j = 0; j < 4; j++) {
            float bs = b1[mt * 16 + r4 + j];
            pacc[mt][0][j] = bs;
            pacc[mt][1][j] = bs;
        }
    }
    #pragma unroll
    for (int ks = 0; ks < 2; ks++) {
        #pragma unroll
        for (int mt = 0; mt < 8; mt++) {
            bf16x8 Ah = *(const bf16x8*)(Aw1 + (((size_t)ks * 2 + 0) * 8 + mt) * 512 + lane * 8);
            bf16x8 Al = *(const bf16x8*)(Aw1 + (((size_t)ks * 2 + 1) * 8 + mt) * 512 + lane * 8);
            #pragma unroll
            for (int ntl = 0; ntl < 2; ntl++) {
                pacc[mt][ntl] = __builtin_amdgcn_mfma_f32_16x16x32_bf16(Ah, Bph[ks][ntl], pacc[mt][ntl], 0, 0, 0);
                pacc[mt][ntl] = __builtin_amdgcn_mfma_f32_16x16x32_bf16(Ah, Bpl[ks][ntl], pacc[mt][ntl], 0, 0, 0);
                pacc[mt][ntl] = __builtin_amdgcn_mfma_f32_16x16x32_bf16(Al, Bph[ks][ntl], pacc[mt][ntl], 0, 0, 0);
            }
        }
    }

    float bb = b2[0];
    #pragma unroll
    for (int ntl = 0; ntl < 2; ntl++) {
        float p = 0.f;
        #pragma unroll
        for (int mt = 0; mt < 8; mt++) {
            p = fmaf(gelu_f(pacc[mt][ntl][0]), w2[mt * 16 + r4 + 0], p);
            p = fmaf(gelu_f(pacc[mt][ntl][1]), w2[mt * 16 + r4 + 1], p);
            p = fmaf(gelu_f(pacc[mt][ntl][2]), w2[mt * 16 + r4 + 2], p);
            p = fmaf(gelu_f(pacc[mt][ntl][3]), w2[mt * 16 + r4 + 3], p);
        }
        p += __shfl_xor(p, 16, 64);
        p += __shfl_xor(p, 32, 64);
        if (lane < 16) {
            int n = n0 + wv * 32 + ntl * 16 + lane;
            out[(size_t)b * 8192 + n] = p + bb;
        }
    }
}

extern "C" void kernel_launch(void* const* d_in, const int* in_sizes, int n_in,
                              void* d_out, int out_size, void* d_ws, size_t ws_size,
                              hipStream_t stream) {
    const float* x  = (const float*)d_in[0];
    const float* lw = (const float*)d_in[1];
    const float* lb = (const float*)d_in[2];
    const float* kr = (const float*)d_in[3];
    const float* ki = (const float*)d_in[4];
    const float* cw = (const float*)d_in[5];
    const float* cb = (const float*)d_in[6];
    const float* w1 = (const float*)d_in[7];
    const float* b1 = (const float*)d_in[8];
    const float* w2 = (const float*)d_in[9];
    const float* b2 = (const float*)d_in[10];
    float* out = (float*)d_out;

    // workspace: Vf 138.4 MB | Ustat 1.05 | Acw 0.08 | WfA2 0.5 | Tdft 1.05 |
    // Aw1 0.03 | Fpart f32: partial mode 17.3 MB (total ~158.5 MB) or atomic
    // fallback 0.5 MB (total ~141.7 MB).
    u16* wsu = (u16*)d_ws;
    size_t VFLEN = (size_t)NB * NBLK * 32768;
    u16* Vf     = wsu;
    u16* Ustat  = Vf + VFLEN;
    u16* AcwBuf = Ustat + (size_t)2 * NT_STAT * 512;
    u16* WfA2   = AcwBuf + (size_t)NL * 8192;
    u16* Tdft   = WfA2 + (size_t)NB * 4096;
    u16* Aw1    = Tdft + (size_t)NSTEPS * 2048;
    u16* fend   = Aw1 + (size_t)16384;
    float* Fpart = (float*)fend;
    size_t base_bytes = (size_t)(fend - wsu) * sizeof(u16);
    size_t need_partial = base_bytes + (size_t)NB * NBLK * 2048 * sizeof(float);
    int atomicMode = (ws_size >= need_partial) ? 0 : 1;
    int fstride = atomicMode ? 2048 : (NBLK * 2048);
    int nblk = atomicMode ? 1 : NBLK;

    kstat<<<dim3(NT_STAT), 256, 0, stream>>>(Ustat);
    kdtab<<<dim3(NSTEPS), 256, 0, stream>>>(Tdft);
    kprep<<<dim3(NL), 256, 0, stream>>>(cw, AcwBuf);
    kprep2<<<dim3(1), 256, 0, stream>>>(w1, Aw1);

    if (atomicMode)
        hipMemsetAsync(Fpart, 0, (size_t)NB * 2048 * sizeof(float), stream);
    klift2<<<dim3(NBLK, NB), 512, 0, stream>>>(x, lw, lb, Vf, Tdft, Fpart,
                                               fstride, atomicMode);

    for (int l = 0; l < NL; l++) {
        kmix<<<dim3(NB, 4), 256, 0, stream>>>(Fpart, kr, ki, cb, WfA2, l,
                                              nblk, fstride);
        if (l < NL - 1) {
            if (atomicMode)
                hipMemsetAsync(Fpart, 0, (size_t)NB * 2048 * sizeof(float), stream);
            kconv<<<dim3(NBLK, NB), 512, 0, stream>>>(Vf,
                    AcwBuf + (size_t)l * 8192, WfA2, Ustat, Tdft, Fpart,
                    fstride, atomicMode);
        } else {
            kconvp<<<dim3(32, NB), 512, 0, stream>>>(Vf,
                    AcwBuf + (size_t)l * 8192, WfA2, Ustat, Aw1,
                    b1, w2, b2, out);
        }
    }
}

// Round 9
// 550.849 us; speedup vs baseline: 2.6771x; 2.3201x over previous
//
#include <hip/hip_runtime.h>
#include <math.h>

// FNO1d: B=64, N=8192, F_IN=2, W=64, L=5, M=16, PAD=9 -> NLEN=8201
#define NLEN 8201
#define NB 64
#define W 64
#define M 16
#define NL 5
#define TWO_PI 6.283185307179586476925286766559
#define NT_STAT 514    // static B-frag n-tiles (n < 8224); OOB tiles clamp there
#define NSTEPS 257     // DFT twiddle A-frag K-steps of 32 (covers n < 8224)
#define NBLK 33        // 33 x 256 = 8448 logical cols (8201 valid, rest junk-safe)

typedef unsigned short u16;
typedef __attribute__((ext_vector_type(8))) short bf16x8;   // MFMA A/B frag (4 VGPR)
typedef __attribute__((ext_vector_type(4))) float f32x4;    // MFMA C/D frag
typedef __attribute__((ext_vector_type(4))) short short4v;
typedef __attribute__((ext_vector_type(8))) short short8v;

// ---- bf16 split-precision helpers (x = hi + lo, both RN bf16) ----
// lo(A)*lo(B) term (~2^-16 relative) dropped everywhere: validated in R8
// (absmax bit-identical 4.88e-4). 3 MFMA per hi/lo pair.
__device__ __forceinline__ u16 bf16rn(float x) {
    unsigned u = __float_as_uint(x);
    unsigned r = (u + 0x7fffu + ((u >> 16) & 1u)) >> 16;
    return (u16)r;
}
__device__ __forceinline__ float bf16tof(u16 h) {
    return __uint_as_float(((unsigned)h) << 16);
}
__device__ __forceinline__ void bf16split(float x, u16& h, u16& lo) {
    h = bf16rn(x);
    lo = bf16rn(x - bf16tof(h));
}

__device__ __forceinline__ short8v cat4(short4v a, short4v b) {
    short8v r;
    r[0] = a[0]; r[1] = a[1]; r[2] = a[2]; r[3] = a[3];
    r[4] = b[0]; r[5] = b[1]; r[6] = b[2]; r[7] = b[3];
    return r;
}

__device__ __forceinline__ void atomicAddF(float* p, float v) {
    __hip_atomic_fetch_add(p, v, __ATOMIC_RELAXED, __HIP_MEMORY_SCOPE_AGENT);
}

// Both MFMA operand sides always use the SAME (lane>>4, e) -> kk bijection, so
// the hardware's exact within-K ordering cancels out of every contraction.
//   main GEMM:     kk(g,e) = g*4 + (e&3) + 16*(e>>2)
//   DFT epilogue:  nloc(g,e) = g*8 + e
//
// v lives in GLOBAL memory pre-fragmented ("Vf"): per (b, blk) a 64 KB tile
// Vf[plane(4)=ks*2+hl][nt(16)][lane(64)][e(8)] of u16. Wave wv's GEMM B-frags
// are the nt = wv*2+ntl slices -> DISJOINT per wave -> loaded straight from
// global to registers (coalesced 16B/lane). The format is an IDENTITY between
// producer epilogue registers and consumer B-frags (enables the last-layer
// conv+projection fusion fully in registers).
//
// LESSONS (R7/R8 regressions): (1) never pass live hv/lv fragment arrays
// through a function boundary or force min-waves bounds -> scratch spill;
// (2) do NOT shrink the DFT-tail LDS via 2-half packW streaming or LDS
// atomicAdd reduction -> DS-pipeline serialization (218us kconv). The proven
// structure is: 64KB static LDS, pack once, store + tree-reduce, per-block
// Fpart partials. Keep it.

// Branchless gelu: A&S 7.1.26 erf (|err| <= 1.5e-7), rcp+exp fast paths.
__device__ __forceinline__ float gelu_f(float x) {
    float s = x * 0.70710678118654752f;
    float a = fabsf(s);
    float t = __builtin_amdgcn_rcpf(fmaf(0.3275911f, a, 1.0f));
    float p = fmaf(1.061405429f, t, -1.453152027f);
    p = fmaf(p, t, 1.421413741f);
    p = fmaf(p, t, -0.284496736f);
    p = fmaf(p, t, 0.254829592f);
    p = p * t;
    float e = __expf(-a * a);
    float er = copysignf(fmaf(-p, e, 1.0f), s);
    float h = 0.5f * x;
    return fmaf(h, er, h);
}

// Static B-frags for main-GEMM ks=2 (U rows 64..95 = [cos1..15|sin1..15|1|0]).
__global__ __launch_bounds__(256) void kstat(u16* __restrict__ Ustat) {
    int nt = blockIdx.x;             // 0..NT_STAT-1
    int t = threadIdx.x;
    for (int s = t; s < 512; s += 256) {
        int lane = s >> 3, e = s & 7;
        int kk = ((lane >> 4) << 2) + (e & 3) + ((e >> 2) << 4);
        int r = 64 + kk;
        int n = nt * 16 + (lane & 15);
        float val;
        if (r < 94) {
            int k = (r < 79) ? (r - 63) : (r - 78);
            long long mm = ((long long)k * (long long)n) % NLEN;
            double th = (TWO_PI / (double)NLEN) * (double)mm;
            double sv, cv;
            sincos(th, &sv, &cv);
            val = (float)((r < 79) ? cv : sv);
        } else {
            val = (r == 94) ? 1.0f : 0.0f;
        }
        u16 h, lo;
        bf16split(val, h, lo);
        size_t base = ((size_t)nt * 64 + lane) * 8 + e;
        Ustat[base] = h;
        Ustat[(size_t)NT_STAT * 512 + base] = lo;
    }
}

// Twiddle A-frags for the fused DFT: Tdft[nstep][kcT(2)][hl(2)][lane][e].
// A[m=kc][n]: kc<16 -> cos(2pi*kc*n/NLEN); kc>=16 -> -sin(2pi*(kc-16)*n/NLEN).
__global__ __launch_bounds__(256) void kdtab(u16* __restrict__ Tdft) {
    int nstep = blockIdx.x;
    int t = threadIdx.x;
    for (int s = t; s < 1024; s += 256) {     // kcT(2) x lane(64) x e(8)
        int e = s & 7, lane = (s >> 3) & 63, kcT = s >> 9;
        int kc = kcT * 16 + (lane & 15);
        int n = nstep * 32 + ((lane >> 4) << 3) + e;
        int k = kc & 15;
        long long m = ((long long)k * (long long)n) % NLEN;
        double th = (TWO_PI / (double)NLEN) * (double)m;
        double sv, cv;
        sincos(th, &sv, &cv);
        float val = (kc < 16) ? (float)cv : (float)(-sv);
        u16 h, lo;
        bf16split(val, h, lo);
        size_t base = (((size_t)nstep * 2 + kcT) * 2) * 512 + lane * 8 + e;
        Tdft[base] = h;
        Tdft[base + 512] = lo;
    }
}

// Pack cw (all 5 layers) into A-frags: AcwBuf[l][ks(2)][hl(2)][mt(4)][lane][e].
__global__ __launch_bounds__(256) void kprep(const float* __restrict__ cw,
                                             u16* __restrict__ AcwBuf) {
    int l = blockIdx.x;
    int t = threadIdx.x;
    const float* cwl = cw + (size_t)l * W * W;
    u16* ob = AcwBuf + (size_t)l * 8192;
    for (int s = t; s < 4096; s += 256) {
        int e = s & 7, lane = (s >> 3) & 63, mt = (s >> 9) & 3, ks = s >> 11;
        int kk = ((lane >> 4) << 2) + (e & 3) + ((e >> 2) << 4);
        int k = ks * 32 + kk;
        int o = mt * 16 + (lane & 15);
        u16 h, lo;
        bf16split(cwl[o * 64 + k], h, lo);
        ob[(((size_t)ks * 2 + 0) * 4 + mt) * 512 + lane * 8 + e] = h;
        ob[(((size_t)ks * 2 + 1) * 4 + mt) * 512 + lane * 8 + e] = lo;
    }
}

// Pack w1 (64k x 128h) into A-frags: Aw1[ks(2)][hl(2)][mt(8)][lane][e].
__global__ __launch_bounds__(256) void kprep2(const float* __restrict__ w1,
                                              u16* __restrict__ Aw1) {
    int t = threadIdx.x;
    for (int s = t; s < 8192; s += 256) {    // ks(2) x mt(8) x lane(64) x e(8)
        int e = s & 7, lane = (s >> 3) & 63, mt = (s >> 9) & 7, ks = s >> 12;
        int kk = ((lane >> 4) << 2) + (e & 3) + ((e >> 2) << 4);
        int k = ks * 32 + kk;
        int h = mt * 16 + (lane & 15);
        u16 hh, lo;
        bf16split(w1[k * 128 + h], hh, lo);
        Aw1[(((size_t)ks * 2 + 0) * 8 + mt) * 512 + lane * 8 + e] = hh;
        Aw1[(((size_t)ks * 2 + 1) * 8 + mt) * 512 + lane * 8 + e] = lo;
    }
}

// Shared DFT tail: outW (lds + wv*4096) already packed; MFMA vs Tdft (6 per
// step, lo*lo dropped), reduce across 8 waves in-place. Partial mode: one
// float4 store per thread into Fpart[b][blk][2048]. Atomic fallback:
// device-scope adds into Fpart[b][2048]. NOTE: takes only the lds pointer
// (no live register arrays cross this boundary).
__device__ __forceinline__ void dft_tail(u16* lds, int wv, int lane, int t,
        int blk, const u16* __restrict__ Tdft, float* __restrict__ FpB,
        int atomicMode) {
    int nstep = blk * 8 + wv;
    if (nstep > NSTEPS - 1) nstep = NSTEPS - 1;   // OOB waves are masked-zero B
    const u16* at = Tdft + (size_t)nstep * 2048;
    bf16x8 Th0 = *(const bf16x8*)(at + lane * 8);
    bf16x8 Tl0 = *(const bf16x8*)(at + 512 + lane * 8);
    bf16x8 Th1 = *(const bf16x8*)(at + 1024 + lane * 8);
    bf16x8 Tl1 = *(const bf16x8*)(at + 1536 + lane * 8);
    f32x4 dacc[2][4];
    #pragma unroll
    for (int kt = 0; kt < 2; kt++)
        #pragma unroll
        for (int ot = 0; ot < 4; ot++) dacc[kt][ot] = (f32x4){0.f, 0.f, 0.f, 0.f};
    const u16* rd = lds + wv * 4096;
    int g = lane >> 4;
    #pragma unroll
    for (int ot = 0; ot < 4; ot++) {
        int oo = ot * 16 + (lane & 15);
        int swz = (oo & 7) << 4;
        bf16x8 Bh = *(const bf16x8*)(rd + (((oo * 128 + g * 16) ^ swz) >> 1));
        bf16x8 Bl = *(const bf16x8*)(rd + (((oo * 128 + 64 + g * 16) ^ swz) >> 1));
        dacc[0][ot] = __builtin_amdgcn_mfma_f32_16x16x32_bf16(Th0, Bh, dacc[0][ot], 0, 0, 0);
        dacc[0][ot] = __builtin_amdgcn_mfma_f32_16x16x32_bf16(Th0, Bl, dacc[0][ot], 0, 0, 0);
        dacc[0][ot] = __builtin_amdgcn_mfma_f32_16x16x32_bf16(Tl0, Bh, dacc[0][ot], 0, 0, 0);
        dacc[1][ot] = __builtin_amdgcn_mfma_f32_16x16x32_bf16(Th1, Bh, dacc[1][ot], 0, 0, 0);
        dacc[1][ot] = __builtin_amdgcn_mfma_f32_16x16x32_bf16(Th1, Bl, dacc[1][ot], 0, 0, 0);
        dacc[1][ot] = __builtin_amdgcn_mfma_f32_16x16x32_bf16(Tl1, Bh, dacc[1][ot], 0, 0, 0);
    }
    // per-wave reduce buffer overwrites own region (reads above complete first)
    float* rw = (float*)lds + wv * 2048;
    #pragma unroll
    for (int kt = 0; kt < 2; kt++)
        #pragma unroll
        for (int ot = 0; ot < 4; ot++) {
            int oo = ot * 16 + (lane & 15);
            int kcb = kt * 16 + ((lane >> 4) << 2);
            rw[(kcb + 0) * 64 + oo] = dacc[kt][ot][0];
            rw[(kcb + 1) * 64 + oo] = dacc[kt][ot][1];
            rw[(kcb + 2) * 64 + oo] = dacc[kt][ot][2];
            rw[(kcb + 3) * 64 + oo] = dacc[kt][ot][3];
        }
    __syncthreads();
    {
        const float* rr = (const float*)lds;
        int idx = t * 4;
        float4 s = *(const float4*)(rr + idx);
        #pragma unroll
        for (int w2 = 1; w2 < 8; w2++) {
            float4 p = *(const float4*)(rr + w2 * 2048 + idx);
            s.x += p.x; s.y += p.y; s.z += p.z; s.w += p.w;
        }
        if (atomicMode) {
            atomicAddF(FpB + idx + 0, s.x);
            atomicAddF(FpB + idx + 1, s.y);
            atomicAddF(FpB + idx + 2, s.z);
            atomicAddF(FpB + idx + 3, s.w);
        } else {
            *(float4*)(FpB + (size_t)blk * 2048 + idx) = s;
        }
    }
}

// Fused lift + forward-DFT: lift tile in acc register layout, Vf fragment
// stores (16B/lane), pack into 64KB LDS, dft_tail.
__global__ __launch_bounds__(512, 4) void klift2(const float* __restrict__ x,
        const float* __restrict__ lw, const float* __restrict__ lb,
        u16* __restrict__ Vf, const u16* __restrict__ Tdft,
        float* __restrict__ Fpart, int fstride, int atomicMode) {
    __shared__ __align__(16) u16 outT[8 * 4096];   // 64 KB
    int t = threadIdx.x;
    int b = blockIdx.y;
    int blk = blockIdx.x;
    int lane = t & 63;
    int wv = __builtin_amdgcn_readfirstlane(t >> 6);
    int r4 = (lane >> 4) << 2;
    u16* vfb = Vf + ((size_t)b * NBLK + blk) * 32768;
    int n0 = blk * 256;

    short4v hv[4][2], lv[4][2];
    #pragma unroll
    for (int ntl = 0; ntl < 2; ntl++) {
        int nt = wv * 2 + ntl;
        int n = n0 + nt * 16 + (lane & 15);
        float x0 = 0.f, x1 = 0.f;
        bool in = (n < 8192);
        if (in) {
            const float* xp = x + ((size_t)b * 8192 + n) * 2;
            x0 = xp[0]; x1 = xp[1];
        }
        #pragma unroll
        for (int mt = 0; mt < 4; mt++) {
            #pragma unroll
            for (int j = 0; j < 4; j++) {
                int o = mt * 16 + r4 + j;
                float val = in ? fmaf(x0, lw[o], fmaf(x1, lw[64 + o], lb[o])) : 0.f;
                u16 h, lo;
                bf16split(val, h, lo);
                hv[mt][ntl][j] = (short)h;
                lv[mt][ntl][j] = (short)lo;
            }
        }
        *(short8v*)(vfb + ((size_t)0 * 16 + nt) * 512 + lane * 8) = cat4(hv[0][ntl], hv[1][ntl]);
        *(short8v*)(vfb + ((size_t)1 * 16 + nt) * 512 + lane * 8) = cat4(lv[0][ntl], lv[1][ntl]);
        *(short8v*)(vfb + ((size_t)2 * 16 + nt) * 512 + lane * 8) = cat4(hv[2][ntl], hv[3][ntl]);
        *(short8v*)(vfb + ((size_t)3 * 16 + nt) * 512 + lane * 8) = cat4(lv[2][ntl], lv[3][ntl]);
    }

    // DFT pack (own-wave region; no cross-wave readers yet -> no barrier)
    u16* outW = outT + wv * 4096;
    #pragma unroll
    for (int ntl = 0; ntl < 2; ntl++) {
        int nl = ntl * 16 + (lane & 15);
        bool ok = (n0 + wv * 32 + nl) <= 8200;
        #pragma unroll
        for (int mt = 0; mt < 4; mt++) {
            #pragma unroll
            for (int j = 0; j < 4; j++) {
                int oo = mt * 16 + r4 + j;
                u16 h  = ok ? (u16)hv[mt][ntl][j] : (u16)0;
                u16 lo = ok ? (u16)lv[mt][ntl][j] : (u16)0;
                int raw = oo * 128 + nl * 2;
                int swz = (oo & 7) << 4;
                outW[(raw ^ swz) >> 1] = h;
                outW[((raw + 64) ^ swz) >> 1] = lo;
            }
        }
    }
    dft_tail(outT, wv, lane, t, blk, Tdft, Fpart + (size_t)b * fstride, atomicMode);
}

// Write one W-matrix value (row 64+kk, col o) into per-b ks2 A-frags (hi+lo).
__device__ __forceinline__ void wfrag(u16* wb2, int mt, int kk, int ol, float val) {
    int lane = ol + (((kk & 15) >> 2) << 4);
    int e = (kk & 3) + ((kk >> 4) << 2);
    u16 h, lo;
    bf16split(val, h, lo);
    wb2[(size_t)mt * 512 + lane * 8 + e] = h;
    wb2[(size_t)(4 + mt) * 512 + lane * 8 + e] = lo;
}

// Mode mix. Phase 1: reduce Fpart[b][0..nblk) into LDS Fs[8][64]. Phase 2:
// P = F*kern, emit spectral A-frags WfA2[b].
__global__ __launch_bounds__(256) void kmix(const float* __restrict__ Fpart,
        const float* __restrict__ kr, const float* __restrict__ ki,
        const float* __restrict__ cb, u16* __restrict__ WfA2, int l,
        int nblk, int fstride) {
    int b = blockIdx.x, kg = blockIdx.y;
    int t = threadIdx.x;
    int o = t & 63, ii = t >> 6;
    __shared__ float Fs[8][64];
    {
        const float* fp = Fpart + (size_t)b * fstride;
        int r0 = t >> 6, oo = t & 63;
        int kc0 = kg * 4 + r0;          // cos rows (Re)
        int kc1 = 16 + kg * 4 + r0;     // sin rows (Im)
        float s0 = 0.f, s1 = 0.f, s2 = 0.f, s3 = 0.f;
        int blk = 0;
        for (; blk + 2 <= nblk; blk += 2) {
            s0 += fp[(size_t)blk * 2048 + kc0 * 64 + oo];
            s1 += fp[(size_t)(blk + 1) * 2048 + kc0 * 64 + oo];
            s2 += fp[(size_t)blk * 2048 + kc1 * 64 + oo];
            s3 += fp[(size_t)(blk + 1) * 2048 + kc1 * 64 + oo];
        }
        if (blk < nblk) {
            s0 += fp[(size_t)blk * 2048 + kc0 * 64 + oo];
            s2 += fp[(size_t)blk * 2048 + kc1 * 64 + oo];
        }
        Fs[r0][oo] = s0 + s1;
        Fs[4 + r0][oo] = s2 + s3;
    }
    __syncthreads();

    const float* krl = kr + (size_t)l * W * W * M;
    const float* kil = ki + (size_t)l * W * W * M;
    float pr[4] = {0.f, 0.f, 0.f, 0.f}, pi[4] = {0.f, 0.f, 0.f, 0.f};
    for (int i = ii * 16; i < ii * 16 + 16; i++) {
        float4 kr4 = *(const float4*)(krl + ((size_t)i * W + o) * M + kg * 4);
        float4 ki4 = *(const float4*)(kil + ((size_t)i * W + o) * M + kg * 4);
        float re0 = Fs[0][i], im0 = Fs[4][i];
        float re1 = Fs[1][i], im1 = Fs[5][i];
        float re2 = Fs[2][i], im2 = Fs[6][i];
        float re3 = Fs[3][i], im3 = Fs[7][i];
        pr[0] += re0 * kr4.x - im0 * ki4.x;  pi[0] += re0 * ki4.x + im0 * kr4.x;
        pr[1] += re1 * kr4.y - im1 * ki4.y;  pi[1] += re1 * ki4.y + im1 * kr4.y;
        pr[2] += re2 * kr4.z - im2 * ki4.z;  pi[2] += re2 * ki4.z + im2 * kr4.z;
        pr[3] += re3 * kr4.w - im3 * ki4.w;  pi[3] += re3 * ki4.w + im3 * kr4.w;
    }
    __shared__ float red[4][64][8];
    #pragma unroll
    for (int c = 0; c < 4; c++) {
        red[ii][o][2 * c]     = pr[c];
        red[ii][o][2 * c + 1] = pi[c];
    }
    __syncthreads();
    if (ii == 0) {
        u16* wb2 = WfA2 + (size_t)b * 4096;
        int mt = o >> 4, ol = o & 15;
        #pragma unroll
        for (int c = 0; c < 4; c++) {
            int k = kg * 4 + c;
            float sr = red[0][o][2 * c] + red[1][o][2 * c] + red[2][o][2 * c] + red[3][o][2 * c];
            float si = red[0][o][2 * c + 1] + red[1][o][2 * c + 1] + red[2][o][2 * c + 1] + red[3][o][2 * c + 1];
            if (k == 0) {
                wfrag(wb2, mt, 30, ol, cb[l * W + o] + sr * (1.0f / (float)NLEN));
                wfrag(wb2, mt, 31, ol, 0.0f);
            } else {
                wfrag(wb2, mt, k - 1,  ol, sr * (2.0f / (float)NLEN));
                wfrag(wb2, mt, 14 + k, ol, -si * (2.0f / (float)NLEN));
            }
        }
    }
}

// Fused conv + inverse transform + gelu via bf16-split MFMA on fragment-format
// Vf, IN-PLACE, plus fused forward-DFT of the output (layers 0..3).
__global__ __launch_bounds__(512, 4) void kconv(u16* __restrict__ Vf,
        const u16* __restrict__ AcwL, const u16* __restrict__ WfA2,
        const u16* __restrict__ Ustat, const u16* __restrict__ Tdft,
        float* __restrict__ Fpart, int fstride, int atomicMode) {
    __shared__ __align__(16) u16 dlds[8 * 4096];   // 64 KB (DFT pack + reduce)
    int t = threadIdx.x;
    int b = blockIdx.y;
    int blk = blockIdx.x;
    int n0 = blk * 256;
    int lane = t & 63;
    int wv = __builtin_amdgcn_readfirstlane(t >> 6);       // 0..7
    u16* vfb = Vf + ((size_t)b * NBLK + blk) * 32768;
    int nt0 = wv * 2;

    // ---- direct B-frag loads (upfront, all in flight) ----
    bf16x8 Bh[3][2], Bl[3][2];
    #pragma unroll
    for (int ks = 0; ks < 2; ks++)
        #pragma unroll
        for (int ntl = 0; ntl < 2; ntl++) {
            Bh[ks][ntl] = *(const bf16x8*)(vfb + (((size_t)ks * 2 + 0) * 16 + nt0 + ntl) * 512 + lane * 8);
            Bl[ks][ntl] = *(const bf16x8*)(vfb + (((size_t)ks * 2 + 1) * 16 + nt0 + ntl) * 512 + lane * 8);
        }
    #pragma unroll
    for (int ntl = 0; ntl < 2; ntl++) {
        int ntg = (n0 >> 4) + nt0 + ntl;
        if (ntg >= NT_STAT) ntg = NT_STAT - 1;   // OOB cols: finite junk
        Bh[2][ntl] = *(const bf16x8*)(Ustat + ((size_t)ntg * 64 + lane) * 8);
        Bl[2][ntl] = *(const bf16x8*)(Ustat + (size_t)NT_STAT * 512 + ((size_t)ntg * 64 + lane) * 8);
    }

    f32x4 acc[4][2];
    #pragma unroll
    for (int mt = 0; mt < 4; mt++)
        #pragma unroll
        for (int j = 0; j < 2; j++)
            acc[mt][j] = (f32x4){0.f, 0.f, 0.f, 0.f};

    const u16* wb2 = WfA2 + (size_t)b * 4096;
    #pragma unroll
    for (int ks = 0; ks < 3; ks++) {
        const u16* ab = (ks < 2) ? (AcwL + (size_t)ks * 4096) : wb2;
        #pragma unroll
        for (int mt = 0; mt < 4; mt++) {
            bf16x8 Ah = *(const bf16x8*)(ab + (size_t)mt * 512 + lane * 8);
            bf16x8 Al = *(const bf16x8*)(ab + (size_t)(4 + mt) * 512 + lane * 8);
            #pragma unroll
            for (int ntl = 0; ntl < 2; ntl++) {
                acc[mt][ntl] = __builtin_amdgcn_mfma_f32_16x16x32_bf16(Ah, Bh[ks][ntl], acc[mt][ntl], 0, 0, 0);
                acc[mt][ntl] = __builtin_amdgcn_mfma_f32_16x16x32_bf16(Ah, Bl[ks][ntl], acc[mt][ntl], 0, 0, 0);
                acc[mt][ntl] = __builtin_amdgcn_mfma_f32_16x16x32_bf16(Al, Bh[ks][ntl], acc[mt][ntl], 0, 0, 0);
            }
        }
    }

    // ---- epilogue: gelu + split + full-width fragment stores ----
    int r4 = (lane >> 4) << 2;
    short4v hv[4][2], lv[4][2];
    #pragma unroll
    for (int ntl = 0; ntl < 2; ntl++) {
        int nt = nt0 + ntl;
        #pragma unroll
        for (int mt = 0; mt < 4; mt++) {
            #pragma unroll
            for (int j = 0; j < 4; j++) {
                float gv = gelu_f(acc[mt][ntl][j]);
                u16 h, lo;
                bf16split(gv, h, lo);
                hv[mt][ntl][j] = (short)h;
                lv[mt][ntl][j] = (short)lo;
            }
        }
        *(short8v*)(vfb + ((size_t)0 * 16 + nt) * 512 + lane * 8) = cat4(hv[0][ntl], hv[1][ntl]);
        *(short8v*)(vfb + ((size_t)1 * 16 + nt) * 512 + lane * 8) = cat4(lv[0][ntl], lv[1][ntl]);
        *(short8v*)(vfb + ((size_t)2 * 16 + nt) * 512 + lane * 8) = cat4(hv[2][ntl], hv[3][ntl]);
        *(short8v*)(vfb + ((size_t)3 * 16 + nt) * 512 + lane * 8) = cat4(lv[2][ntl], lv[3][ntl]);
    }

    // ---- fused forward-DFT of the output tile ----
    {
        u16* outW = dlds + wv * 4096;          // per-wave region
        #pragma unroll
        for (int ntl = 0; ntl < 2; ntl++) {
            int nl = ntl * 16 + (lane & 15);
            bool ok = (n0 + wv * 32 + nl) <= 8200;
            #pragma unroll
            for (int mt = 0; mt < 4; mt++) {
                #pragma unroll
                for (int j = 0; j < 4; j++) {
                    int oo = mt * 16 + r4 + j;
                    u16 h  = ok ? (u16)hv[mt][ntl][j] : (u16)0;
                    u16 lo = ok ? (u16)lv[mt][ntl][j] : (u16)0;
                    int raw = oo * 128 + nl * 2;
                    int swz = (oo & 7) << 4;
                    outW[(raw ^ swz) >> 1] = h;
                    outW[((raw + 64) ^ swz) >> 1] = lo;
                }
            }
        }
        dft_tail(dlds, wv, lane, t, blk, Tdft, Fpart + (size_t)b * fstride, atomicMode);
    }
}

// LAST LAYER fused conv + gelu + projection: conv result never touches memory.
// Grid (32, NB): the blk=32 pad tile of v5 is unused by the projection.
__global__ __launch_bounds__(512, 3) void kconvp(const u16* __restrict__ Vf,
        const u16* __restrict__ AcwL, const u16* __restrict__ WfA2,
        const u16* __restrict__ Ustat, const u16* __restrict__ Aw1,
        const float* __restrict__ b1, const float* __restrict__ w2,
        const float* __restrict__ b2, float* __restrict__ out) {
    int t = threadIdx.x;
    int b = blockIdx.y;
    int blk = blockIdx.x;                 // 0..31, n < 8192 only
    int n0 = blk * 256;
    int lane = t & 63;
    int wv = __builtin_amdgcn_readfirstlane(t >> 6);
    const u16* vfb = Vf + ((size_t)b * NBLK + blk) * 32768;
    int nt0 = wv * 2;

    // ---- conv B-frag loads ----
    bf16x8 Bh[3][2], Bl[3][2];
    #pragma unroll
    for (int ks = 0; ks < 2; ks++)
        #pragma unroll
        for (int ntl = 0; ntl < 2; ntl++) {
            Bh[ks][ntl] = *(const bf16x8*)(vfb + (((size_t)ks * 2 + 0) * 16 + nt0 + ntl) * 512 + lane * 8);
            Bl[ks][ntl] = *(const bf16x8*)(vfb + (((size_t)ks * 2 + 1) * 16 + nt0 + ntl) * 512 + lane * 8);
        }
    #pragma unroll
    for (int ntl = 0; ntl < 2; ntl++) {
        int ntg = (n0 >> 4) + nt0 + ntl;             // < 512 always here
        Bh[2][ntl] = *(const bf16x8*)(Ustat + ((size_t)ntg * 64 + lane) * 8);
        Bl[2][ntl] = *(const bf16x8*)(Ustat + (size_t)NT_STAT * 512 + ((size_t)ntg * 64 + lane) * 8);
    }

    f32x4 acc[4][2];
    #pragma unroll
    for (int mt = 0; mt < 4; mt++)
        #pragma unroll
        for (int j = 0; j < 2; j++)
            acc[mt][j] = (f32x4){0.f, 0.f, 0.f, 0.f};

    const u16* wb2 = WfA2 + (size_t)b * 4096;
    #pragma unroll
    for (int ks = 0; ks < 3; ks++) {
        const u16* ab = (ks < 2) ? (AcwL + (size_t)ks * 4096) : wb2;
        #pragma unroll
        for (int mt = 0; mt < 4; mt++) {
            bf16x8 Ah = *(const bf16x8*)(ab + (size_t)mt * 512 + lane * 8);
            bf16x8 Al = *(const bf16x8*)(ab + (size_t)(4 + mt) * 512 + lane * 8);
            #pragma unroll
            for (int ntl = 0; ntl < 2; ntl++) {
                acc[mt][ntl] = __builtin_amdgcn_mfma_f32_16x16x32_bf16(Ah, Bh[ks][ntl], acc[mt][ntl], 0, 0, 0);
                acc[mt][ntl] = __builtin_amdgcn_mfma_f32_16x16x32_bf16(Ah, Bl[ks][ntl], acc[mt][ntl], 0, 0, 0);
                acc[mt][ntl] = __builtin_amdgcn_mfma_f32_16x16x32_bf16(Al, Bh[ks][ntl], acc[mt][ntl], 0, 0, 0);
            }
        }
    }

    // ---- gelu + split directly into projection B-frags (register identity) ----
    bf16x8 Bph[2][2], Bpl[2][2];
    int r4 = (lane >> 4) << 2;
    #pragma unroll
    for (int ntl = 0; ntl < 2; ntl++) {
        #pragma unroll
        for (int mt = 0; mt < 4; mt++) {
            #pragma unroll
            for (int j = 0; j < 4; j++) {
                float gv = gelu_f(acc[mt][ntl][j]);
                u16 h, lo;
                bf16split(gv, h, lo);
                Bph[mt >> 1][ntl][(mt & 1) * 4 + j] = (short)h;
                Bpl[mt >> 1][ntl][(mt & 1) * 4 + j] = (short)lo;
            }
        }
    }

    // ---- projection GEMM ----
    f32x4 pacc[8][2];
    #pragma unroll
    for (int mt = 0; mt < 8; mt++) {
        #pragma unroll
        for (int j = 0; j < 4; j++) {
            float bs = b1[mt * 16 + r4 + j];
            pacc[mt][0][j] = bs;
            pacc[mt][1][j] = bs;
        }
    }
    #pragma unroll
    for (int ks = 0; ks < 2; ks++) {
        #pragma unroll
        for (int mt = 0; mt < 8; mt++) {
            bf16x8 Ah = *(const bf16x8*)(Aw1 + (((size_t)ks * 2 + 0) * 8 + mt) * 512 + lane * 8);
            bf16x8 Al = *(const bf16x8*)(Aw1 + (((size_t)ks * 2 + 1) * 8 + mt) * 512 + lane * 8);
            #pragma unroll
            for (int ntl = 0; ntl < 2; ntl++) {
                pacc[mt][ntl] = __builtin_amdgcn_mfma_f32_16x16x32_bf16(Ah, Bph[ks][ntl], pacc[mt][ntl], 0, 0, 0);
                pacc[mt][ntl] = __builtin_amdgcn_mfma_f32_16x16x32_bf16(Ah, Bpl[ks][ntl], pacc[mt][ntl], 0, 0, 0);
                pacc[mt][ntl] = __builtin_amdgcn_mfma_f32_16x16x32_bf16(Al, Bph[ks][ntl], pacc[mt][ntl], 0, 0, 0);
            }
        }
    }

    float bb = b2[0];
    #pragma unroll
    for (int ntl = 0; ntl < 2; ntl++) {
        float p = 0.f;
        #pragma unroll
        for (int mt = 0; mt < 8; mt++) {
            p = fmaf(gelu_f(pacc[mt][ntl][0]), w2[mt * 16 + r4 + 0], p);
            p = fmaf(gelu_f(pacc[mt][ntl][1]), w2[mt * 16 + r4 + 1], p);
            p = fmaf(gelu_f(pacc[mt][ntl][2]), w2[mt * 16 + r4 + 2], p);
            p = fmaf(gelu_f(pacc[mt][ntl][3]), w2[mt * 16 + r4 + 3], p);
        }
        p += __shfl_xor(p, 16, 64);
        p += __shfl_xor(p, 32, 64);
        if (lane < 16) {
            int n = n0 + wv * 32 + ntl * 16 + lane;
            out[(size_t)b * 8192 + n] = p + bb;
        }
    }
}

extern "C" void kernel_launch(void* const* d_in, const int* in_sizes, int n_in,
                              void* d_out, int out_size, void* d_ws, size_t ws_size,
                              hipStream_t stream) {
    const float* x  = (const float*)d_in[0];
    const float* lw = (const float*)d_in[1];
    const float* lb = (const float*)d_in[2];
    const float* kr = (const float*)d_in[3];
    const float* ki = (const float*)d_in[4];
    const float* cw = (const float*)d_in[5];
    const float* cb = (const float*)d_in[6];
    const float* w1 = (const float*)d_in[7];
    const float* b1 = (const float*)d_in[8];
    const float* w2 = (const float*)d_in[9];
    const float* b2 = (const float*)d_in[10];
    float* out = (float*)d_out;

    // workspace: Vf 138.4 MB | Ustat 1.05 | Acw 0.08 | WfA2 0.5 | Tdft 1.05 |
    // Aw1 0.03 | Fpart f32: partial mode 17.3 MB (total ~158.5 MB) or atomic
    // fallback 0.5 MB (total ~141.7 MB).
    u16* wsu = (u16*)d_ws;
    size_t VFLEN = (size_t)NB * NBLK * 32768;
    u16* Vf     = wsu;
    u16* Ustat  = Vf + VFLEN;
    u16* AcwBuf = Ustat + (size_t)2 * NT_STAT * 512;
    u16* WfA2   = AcwBuf + (size_t)NL * 8192;
    u16* Tdft   = WfA2 + (size_t)NB * 4096;
    u16* Aw1    = Tdft + (size_t)NSTEPS * 2048;
    u16* fend   = Aw1 + (size_t)16384;
    float* Fpart = (float*)fend;
    size_t base_bytes = (size_t)(fend - wsu) * sizeof(u16);
    size_t need_partial = base_bytes + (size_t)NB * NBLK * 2048 * sizeof(float);
    int atomicMode = (ws_size >= need_partial) ? 0 : 1;
    int fstride = atomicMode ? 2048 : (NBLK * 2048);
    int nblk = atomicMode ? 1 : NBLK;

    kstat<<<dim3(NT_STAT), 256, 0, stream>>>(Ustat);
    kdtab<<<dim3(NSTEPS), 256, 0, stream>>>(Tdft);
    kprep<<<dim3(NL), 256, 0, stream>>>(cw, AcwBuf);
    kprep2<<<dim3(1), 256, 0, stream>>>(w1, Aw1);

    if (atomicMode)
        hipMemsetAsync(Fpart, 0, (size_t)NB * 2048 * sizeof(float), stream);
    klift2<<<dim3(NBLK, NB), 512, 0, stream>>>(x, lw, lb, Vf, Tdft, Fpart,
                                               fstride, atomicMode);

    for (int l = 0; l < NL; l++) {
        kmix<<<dim3(NB, 4), 256, 0, stream>>>(Fpart, kr, ki, cb, WfA2, l,
                                              nblk, fstride);
        if (l < NL - 1) {
            if (atomicMode)
                hipMemsetAsync(Fpart, 0, (size_t)NB * 2048 * sizeof(float), stream);
            kconv<<<dim3(NBLK, NB), 512, 0, stream>>>(Vf,
                    AcwBuf + (size_t)l * 8192, WfA2, Ustat, Tdft, Fpart,
                    fstride, atomicMode);
        } else {
            kconvp<<<dim3(32, NB), 512, 0, stream>>>(Vf,
                    AcwBuf + (size_t)l * 8192, WfA2, Ustat, Aw1,
                    b1, w2, b2, out);
        }
    }
}